// Round 2
// baseline (2395.192 us; speedup 1.0000x reference)
//
#include <hip/hip_runtime.h>
#include <stdint.h>

#define THETA 10.0

__device__ __forceinline__ double srm_val(int k) {
    double t = (double)k;
    return (t * 0.1) * exp(1.0 - t * 0.1);
}
__device__ __forceinline__ double ref_val(int d) {   // refractory kernel at offset d (1..32)
    double t = (double)d;
    return -20.0 * t * exp(1.0 - t);
}

// ---------------------------------------------------------------------------
// K1: px[n][c][t] = sum_k srm[k] * x[n][c][t-k]   (psp over time, pre-dense)
__global__ __launch_bounds__(256) void k_psp_time(const float* __restrict__ x,
                                                  double* __restrict__ px) {
    __shared__ double srm[100];
    int tid = threadIdx.x;
    if (tid < 100) srm[tid] = srm_val(tid);
    __syncthreads();
    int row = blockIdx.x >> 1;                 // n*156 + c
    int t = ((blockIdx.x & 1) << 8) + tid;
    if (t >= 500) return;
    const float* xr = x + (size_t)row * 500;
    int kmax = t < 99 ? t : 99;
    double acc = 0.0;
    for (int k = 0; k <= kmax; ++k) acc += srm[k] * (double)xr[t - k];
    px[(size_t)row * 500 + t] = acc;
}

// ---------------------------------------------------------------------------
// Fused layer A1: dense (GEMM 64h x 64t tile, 4x4 micro) + in-block spike scan.
// grid (n=64, hb=8), block 256. s1[n][t][h] uint8.
__global__ __launch_bounds__(256) void k_fused_A(const double* __restrict__ px,
                                                 const float* __restrict__ w1,
                                                 uint8_t* __restrict__ s1) {
    __shared__ double At[16][65];   // w chunk  [c][h]
    __shared__ double Bt[16][65];   // px chunk [c][t]
    __shared__ double uT[64][65];   // u tile   [t][h]
    __shared__ double refk[32];
    int tid = threadIdx.x;
    if (tid < 32) refk[tid] = ref_val(tid + 1);
    int n = blockIdx.x, hb = blockIdx.y;
    int th = tid & 15, tj = tid >> 4;
    const double* pxn = px + (size_t)n * 156 * 500;
    const float* wbase = w1 + (size_t)hb * 64 * 156;
    unsigned mask = 0;   // spike history, used by wave 0 lanes only (lane = h)
    for (int t0 = 0; t0 < 500; t0 += 64) {
        int TT = (500 - t0 < 64) ? (500 - t0) : 64;
        double acc[4][4];
#pragma unroll
        for (int i = 0; i < 4; ++i)
#pragma unroll
            for (int j = 0; j < 4; ++j) acc[i][j] = 0.0;
        for (int c0 = 0; c0 < 156; c0 += 16) {
            int KK = (156 - c0 < 16) ? (156 - c0) : 16;
            __syncthreads();
            for (int e = tid; e < 1024; e += 256) {       // At: 64h x 16c
                int hh = e >> 4, kk = e & 15;
                if (kk < KK) At[kk][hh] = (double)wbase[hh * 156 + c0 + kk];
            }
            for (int e = tid; e < 1024; e += 256) {       // Bt: 16c x 64t
                int tt = e & 63, kk = e >> 6;
                if (kk < KK) {
                    double v = 0.0;
                    if (t0 + tt < 500) v = pxn[(size_t)(c0 + kk) * 500 + t0 + tt];
                    Bt[kk][tt] = v;
                }
            }
            __syncthreads();
            for (int k = 0; k < KK; ++k) {
                double a0 = At[k][th], a1 = At[k][th + 16], a2 = At[k][th + 32], a3 = At[k][th + 48];
                double b0 = Bt[k][tj], b1 = Bt[k][tj + 16], b2 = Bt[k][tj + 32], b3 = Bt[k][tj + 48];
                acc[0][0] += a0 * b0; acc[0][1] += a0 * b1; acc[0][2] += a0 * b2; acc[0][3] += a0 * b3;
                acc[1][0] += a1 * b0; acc[1][1] += a1 * b1; acc[1][2] += a1 * b2; acc[1][3] += a1 * b3;
                acc[2][0] += a2 * b0; acc[2][1] += a2 * b1; acc[2][2] += a2 * b2; acc[2][3] += a2 * b3;
                acc[3][0] += a3 * b0; acc[3][1] += a3 * b1; acc[3][2] += a3 * b2; acc[3][3] += a3 * b3;
            }
        }
        __syncthreads();
#pragma unroll
        for (int i = 0; i < 4; ++i)
#pragma unroll
            for (int j = 0; j < 4; ++j) uT[tj + 16 * j][th + 16 * i] = acc[i][j];
        __syncthreads();
        if (tid < 64) {
            for (int tt0 = 0; tt0 < TT; tt0 += 8) {
                int TB = (TT - tt0 < 8) ? (TT - tt0) : 8;
                double vb[8];
#pragma unroll
                for (int i = 0; i < 8; ++i) if (i < TB) vb[i] = uT[tt0 + i][tid];
                for (int i = 0; i < TB; ++i) {
                    double v = vb[i];
                    unsigned m = mask;
                    while (m) { int d = __builtin_ctz(m); v += refk[d]; m &= m - 1; }
                    int s = (v >= THETA) ? 1 : 0;
                    mask = (mask << 1) | (unsigned)s;
                    s1[((size_t)n * 500 + (t0 + tt0 + i)) * 512 + hb * 64 + tid] = (uint8_t)s;
                }
            }
        }
    }
}

// ---------------------------------------------------------------------------
// K3/KB3: a_t[t][row20] = sum_h w[o][h] * s[n][t][h]  (spikes are 0/1 bytes)
// row20 = n*20+o; output stride 1280.
__global__ __launch_bounds__(256) void k_dense2(const uint8_t* __restrict__ s,
                                                const float* __restrict__ w,
                                                double* __restrict__ a, int T) {
    __shared__ float wt[512 * 20];
    int tid = threadIdx.x;
    for (int e = tid; e < 512 * 20; e += 256) { int o = e / 512, h = e % 512; wt[h * 20 + o] = w[e]; }
    __syncthreads();
    int gid = blockIdx.x * 256 + tid;
    if (gid >= 64 * T) return;
    int n = gid / T, t = gid % T;
    const uint64_t* sw = (const uint64_t*)(s + ((size_t)n * T + t) * 512);
    double acc[20];
#pragma unroll
    for (int o = 0; o < 20; ++o) acc[o] = 0.0;
    for (int wd = 0; wd < 64; ++wd) {
        uint64_t mw = sw[wd] & 0x0101010101010101ULL;
        while (mw) {
            int b = __builtin_ctzll(mw);
            int h = wd * 8 + (b >> 3);
            const float* wp = wt + h * 20;
#pragma unroll
            for (int o = 0; o < 20; ++o) acc[o] += (double)wp[o];
            mw &= mw - 1;
        }
    }
#pragma unroll
    for (int o = 0; o < 20; ++o) a[(size_t)t * 1280 + n * 20 + o] = acc[o];
}

// ---------------------------------------------------------------------------
// K4a/KB4a: p[t][row] = sum_k srm[k]*a[t-k][row]  ([t][1280] layout, coalesced)
__global__ __launch_bounds__(256) void k_psp_rows_T(const double* __restrict__ a,
                                                    double* __restrict__ p,
                                                    int total) {
    __shared__ double srm[100];
    int tid = threadIdx.x;
    if (tid < 100) srm[tid] = srm_val(tid);
    __syncthreads();
    int gid = blockIdx.x * 256 + tid;
    if (gid >= total) return;
    int t = gid / 1280, row = gid - t * 1280;
    int kmax = t < 99 ? t : 99;
    double acc = 0.0;
    for (int k = 0; k <= kmax; ++k) acc += srm[k] * a[(size_t)(t - k) * 1280 + row];
    p[gid] = acc;
}

// ---------------------------------------------------------------------------
// K4b/KB4b: sequential spike scan per row; p is [t][1280]; batched prefetch.
__global__ __launch_bounds__(256) void k_scan_out_T(const double* __restrict__ p,
                                                    float* __restrict__ out,
                                                    int T, int off) {
    __shared__ double refk[32];
    int tid = threadIdx.x;
    if (tid < 32) refk[tid] = ref_val(tid + 1);
    __syncthreads();
    int row = blockIdx.x * 256 + tid;
    if (row >= 1280) return;
    float* orow = out + (size_t)row * 656 + off;
    unsigned mask = 0;
    for (int t0 = 0; t0 < T; t0 += 20) {
        int TB = (T - t0 < 20) ? (T - t0) : 20;
        double vb[20];
#pragma unroll
        for (int i = 0; i < 20; ++i) if (i < TB) vb[i] = p[(size_t)(t0 + i) * 1280 + row];
        for (int i = 0; i < TB; ++i) {
            double v = vb[i];
            unsigned m = mask;
            while (m) { int d = __builtin_ctz(m); v += refk[d]; m &= m - 1; }
            int s = (v >= THETA) ? 1 : 0;
            mask = (mask << 1) | (unsigned)s;
            orow[t0 + i] = (float)s;
        }
    }
}

// ---------------------------------------------------------------------------
// KB1: q[n][j][t] = sum_k srm[k] * x[n][perm[j-k]][t]   (psp over taxel axis)
__global__ __launch_bounds__(256) void k_psp_loc(const float* __restrict__ x,
                                                 const int* __restrict__ perm,
                                                 double* __restrict__ q) {
    __shared__ double srm[100];
    __shared__ int pl[156];
    int tid = threadIdx.x;
    if (tid < 100) srm[tid] = srm_val(tid);
    if (tid < 156) pl[tid] = perm[tid];
    __syncthreads();
    int b = blockIdx.x;
    int row = b >> 1;                  // n*156 + j
    int n = row / 156, j = row % 156;
    int t = ((b & 1) << 8) + tid;
    if (t >= 500) return;
    int kmax = j < 99 ? j : 99;
    double acc = 0.0;
    const float* xn = x + (size_t)n * 156 * 500;
    for (int k = 0; k <= kmax; ++k) {
        int c = pl[j - k];
        acc += srm[k] * (double)xn[(size_t)c * 500 + t];
    }
    q[(size_t)row * 500 + t] = acc;
}

// ---------------------------------------------------------------------------
// KB2: u1b[j][n*512+h] = sum_t w_loc1[h][t] * q[n][j][t]   (fp64 tiled GEMM)
// h on fast lane index -> coalesced stores in [j][nh] layout.
__global__ __launch_bounds__(256) void k_gemm_loc(const double* __restrict__ q,
                                                  const float* __restrict__ wl1,
                                                  double* __restrict__ u1b) {
    __shared__ double At[16][65];   // w    [k][h]
    __shared__ double Bt[16][65];   // q    [k][j]
    int tid = threadIdx.x;
    int n = blockIdx.x, hb = blockIdx.y, jb = blockIdx.z;
    int th = tid & 15, tj = tid >> 4;
    double acc[4][4];
#pragma unroll
    for (int i = 0; i < 4; ++i)
#pragma unroll
        for (int jj = 0; jj < 4; ++jj) acc[i][jj] = 0.0;
    const double* qn = q + (size_t)n * 156 * 500;
    for (int k0 = 0; k0 < 500; k0 += 16) {
        int KK = (500 - k0 < 16) ? (500 - k0) : 16;
        __syncthreads();
        for (int e = tid; e < 1024; e += 256) {
            int hh = e >> 4, kk = e & 15;
            double v = 0.0;
            if (kk < KK) v = (double)wl1[(size_t)(hb * 64 + hh) * 500 + k0 + kk];
            At[kk][hh] = v;
        }
        for (int e = tid; e < 1024; e += 256) {
            int jj2 = e >> 4, kk = e & 15;
            int j = jb * 64 + jj2;
            double v = 0.0;
            if (j < 156 && kk < KK) v = qn[(size_t)j * 500 + k0 + kk];
            Bt[kk][jj2] = v;
        }
        __syncthreads();
        for (int k = 0; k < KK; ++k) {
            double a0 = At[k][th], a1 = At[k][th + 16], a2v = At[k][th + 32], a3 = At[k][th + 48];
            double b0 = Bt[k][tj], b1 = Bt[k][tj + 16], b2 = Bt[k][tj + 32], b3 = Bt[k][tj + 48];
            acc[0][0] += a0 * b0; acc[0][1] += a0 * b1; acc[0][2] += a0 * b2; acc[0][3] += a0 * b3;
            acc[1][0] += a1 * b0; acc[1][1] += a1 * b1; acc[1][2] += a1 * b2; acc[1][3] += a1 * b3;
            acc[2][0] += a2v * b0; acc[2][1] += a2v * b1; acc[2][2] += a2v * b2; acc[2][3] += a2v * b3;
            acc[3][0] += a3 * b0; acc[3][1] += a3 * b1; acc[3][2] += a3 * b2; acc[3][3] += a3 * b3;
        }
    }
#pragma unroll
    for (int jj = 0; jj < 4; ++jj) {
        int j = jb * 64 + tj + 16 * jj;
        if (j >= 156) continue;
#pragma unroll
        for (int i = 0; i < 4; ++i) {
            int h = hb * 64 + th + 16 * i;
            u1b[(size_t)j * 32768 + n * 512 + h] = acc[i][jj];
        }
    }
}

// ---------------------------------------------------------------------------
// KB2-scan: spike scan over j per (n,h); u1b is [j][n*512+h] -> coalesced.
__global__ __launch_bounds__(256) void k_scan_loc1(const double* __restrict__ u1b,
                                                   uint8_t* __restrict__ s1b) {
    __shared__ double refk[32];
    int tid = threadIdx.x;
    if (tid < 32) refk[tid] = ref_val(tid + 1);
    __syncthreads();
    int gid = blockIdx.x * 256 + tid;     // n*512 + h
    int n = gid >> 9, h = gid & 511;
    unsigned mask = 0;
    for (int j0 = 0; j0 < 156; j0 += 12) {
        int JB = (156 - j0 < 12) ? (156 - j0) : 12;
        double vb[12];
#pragma unroll
        for (int i = 0; i < 12; ++i) if (i < JB) vb[i] = u1b[(size_t)(j0 + i) * 32768 + gid];
        for (int i = 0; i < JB; ++i) {
            double v = vb[i];
            unsigned m = mask;
            while (m) { int d = __builtin_ctz(m); v += refk[d]; m &= m - 1; }
            int s = (v >= THETA) ? 1 : 0;
            mask = (mask << 1) | (unsigned)s;
            s1b[((size_t)n * 156 + (j0 + i)) * 512 + h] = (uint8_t)s;
        }
    }
}

// ---------------------------------------------------------------------------
extern "C" void kernel_launch(void* const* d_in, const int* in_sizes, int n_in,
                              void* d_out, int out_size, void* d_ws, size_t ws_size,
                              hipStream_t stream) {
    const float* x      = (const float*)d_in[0];
    const float* w_fc1  = (const float*)d_in[1];
    const float* w_fc2  = (const float*)d_in[2];
    const float* w_loc1 = (const float*)d_in[3];
    const float* w_loc2 = (const float*)d_in[4];
    const int*   perm   = (const int*)d_in[5];
    float* out = (float*)d_out;
    char* ws = (char*)d_ws;

    // workspace layout (bytes); path B overlays path A's dead buffers
    double*  px  = (double*)(ws + 0);              // 39,936,000 B (also q for path B)
    uint8_t* s1  = (uint8_t*)(ws + 39936000);      // 16,384,000 B
    double*  a2  = (double*)(ws + 56320000);       //  5,120,000 B  [t][1280]
    double*  p2  = (double*)(ws + 61440000);       //  5,120,000 B  [t][1280]
    double*  q   = px;
    double*  u1b = (double*)(ws + 39936000);       // 40,894,464 B (overlays s1/a2/p2)
    uint8_t* s1b = (uint8_t*)(ws + 80830464);      //  5,111,808 B
    double*  a2b = (double*)(ws + 85942272);       //  1,597,440 B  [j][1280]
    double*  p2b = (double*)(ws + 87539712);       //  1,597,440 B  [j][1280]
    (void)ws_size; (void)in_sizes; (void)n_in; (void)out_size;

    // ---- temporal path ----
    k_psp_time<<<19968, 256, 0, stream>>>(x, px);
    dim3 g2(64, 8);
    k_fused_A<<<g2, 256, 0, stream>>>(px, w_fc1, s1);
    k_dense2<<<125, 256, 0, stream>>>(s1, w_fc2, a2, 500);
    k_psp_rows_T<<<2500, 256, 0, stream>>>(a2, p2, 500 * 1280);
    k_scan_out_T<<<5, 256, 0, stream>>>(p2, out, 500, 0);

    // ---- location path ----
    k_psp_loc<<<19968, 256, 0, stream>>>(x, perm, q);
    dim3 gb(64, 8, 3);
    k_gemm_loc<<<gb, 256, 0, stream>>>(q, w_loc1, u1b);
    k_scan_loc1<<<128, 256, 0, stream>>>(u1b, s1b);
    k_dense2<<<39, 256, 0, stream>>>(s1b, w_loc2, a2b, 156);
    k_psp_rows_T<<<780, 256, 0, stream>>>(a2b, p2b, 156 * 1280);
    k_scan_out_T<<<5, 256, 0, stream>>>(p2b, out, 156, 500);
}

// Round 3
// 2097.816 us; speedup vs baseline: 1.1418x; 1.1418x over previous
//
#include <hip/hip_runtime.h>
#include <stdint.h>

#define THETA 10.0

__device__ __forceinline__ double srm_val(int k) {
    double t = (double)k;
    return (t * 0.1) * exp(1.0 - t * 0.1);
}
__device__ __forceinline__ double ref_val(int d) {   // refractory kernel at offset d (1..32)
    double t = (double)d;
    return -20.0 * t * exp(1.0 - t);
}

// ---------------------------------------------------------------------------
// K1: px[n][c][t] = sum_k srm[k] * x[n][c][t-k]   (psp over time, pre-dense)
__global__ __launch_bounds__(256) void k_psp_time(const float* __restrict__ x,
                                                  double* __restrict__ px) {
    __shared__ double srm[100];
    int tid = threadIdx.x;
    if (tid < 100) srm[tid] = srm_val(tid);
    __syncthreads();
    int row = blockIdx.x >> 1;                 // n*156 + c
    int t = ((blockIdx.x & 1) << 8) + tid;
    if (t >= 500) return;
    const float* xr = x + (size_t)row * 500;
    int kmax = t < 99 ? t : 99;
    double acc = 0.0;
    for (int k = 0; k <= kmax; ++k) acc += srm[k] * (double)xr[t - k];
    px[(size_t)row * 500 + t] = acc;
}

// ---------------------------------------------------------------------------
// Fused layer A1: dense (GEMM 64h x 64t tile, 4x4 micro) + in-block spike scan.
// grid (n=64, hb=8), block 256. Spikes bit-packed: s1w[(n*500+t)*8 + hb], bit=h&63.
__global__ __launch_bounds__(256) void k_fused_A(const double* __restrict__ px,
                                                 const float* __restrict__ w1,
                                                 uint64_t* __restrict__ s1w) {
    __shared__ double At[16][65];   // w chunk  [c][h]
    __shared__ double Bt[16][65];   // px chunk [c][t]
    __shared__ double uT[64][65];   // u tile   [t][h]
    __shared__ double refk[32];
    int tid = threadIdx.x;
    if (tid < 32) refk[tid] = ref_val(tid + 1);
    int n = blockIdx.x, hb = blockIdx.y;
    int th = tid & 15, tj = tid >> 4;
    const double* pxn = px + (size_t)n * 156 * 500;
    const float* wbase = w1 + (size_t)hb * 64 * 156;
    unsigned mask = 0;   // spike history (wave 0 lanes only; lane = h)
    for (int t0 = 0; t0 < 500; t0 += 64) {
        int TT = (500 - t0 < 64) ? (500 - t0) : 64;   // 64 or 52 (both %4==0)
        double acc[4][4];
#pragma unroll
        for (int i = 0; i < 4; ++i)
#pragma unroll
            for (int j = 0; j < 4; ++j) acc[i][j] = 0.0;
        for (int c0 = 0; c0 < 156; c0 += 16) {
            int KK = (156 - c0 < 16) ? (156 - c0) : 16;
            __syncthreads();
            for (int e = tid; e < 1024; e += 256) {       // At: 64h x 16c
                int hh = e >> 4, kk = e & 15;
                if (kk < KK) At[kk][hh] = (double)wbase[hh * 156 + c0 + kk];
            }
            for (int e = tid; e < 1024; e += 256) {       // Bt: 16c x 64t
                int tt = e & 63, kk = e >> 6;
                if (kk < KK) {
                    double v = 0.0;
                    if (t0 + tt < 500) v = pxn[(size_t)(c0 + kk) * 500 + t0 + tt];
                    Bt[kk][tt] = v;
                }
            }
            __syncthreads();
            for (int k = 0; k < KK; ++k) {
                double a0 = At[k][th], a1 = At[k][th + 16], a2 = At[k][th + 32], a3 = At[k][th + 48];
                double b0 = Bt[k][tj], b1 = Bt[k][tj + 16], b2 = Bt[k][tj + 32], b3 = Bt[k][tj + 48];
                acc[0][0] += a0 * b0; acc[0][1] += a0 * b1; acc[0][2] += a0 * b2; acc[0][3] += a0 * b3;
                acc[1][0] += a1 * b0; acc[1][1] += a1 * b1; acc[1][2] += a1 * b2; acc[1][3] += a1 * b3;
                acc[2][0] += a2 * b0; acc[2][1] += a2 * b1; acc[2][2] += a2 * b2; acc[2][3] += a2 * b3;
                acc[3][0] += a3 * b0; acc[3][1] += a3 * b1; acc[3][2] += a3 * b2; acc[3][3] += a3 * b3;
            }
        }
        __syncthreads();
#pragma unroll
        for (int i = 0; i < 4; ++i)
#pragma unroll
            for (int j = 0; j < 4; ++j) uT[tj + 16 * j][th + 16 * i] = acc[i][j];
        __syncthreads();
        if (tid < 64) {                                   // wave 0 only, lane = h
            for (int tt0 = 0; tt0 < TT; tt0 += 4) {
                double vb[4];
#pragma unroll
                for (int i = 0; i < 4; ++i) vb[i] = uT[tt0 + i][tid];
#pragma unroll
                for (int i = 0; i < 4; ++i) {
                    double v = vb[i];
                    unsigned m = mask;
                    while (m) { int d = __builtin_ctz(m); v += refk[d]; m &= m - 1; }
                    int s = (v >= THETA) ? 1 : 0;
                    mask = (mask << 1) | (unsigned)s;
                    uint64_t bal = __ballot(s != 0);
                    if (tid == 0) s1w[((size_t)n * 500 + (t0 + tt0 + i)) * 8 + hb] = bal;
                }
            }
        }
    }
}

// ---------------------------------------------------------------------------
// K3/KB3: a[t][n*20+o] = sum_h w[o][h] * spike(n,t,h)   (bit-packed spikes)
__global__ __launch_bounds__(256) void k_dense2(const uint64_t* __restrict__ sw,
                                                const float* __restrict__ w,
                                                double* __restrict__ a, int T) {
    __shared__ float wt[512 * 20];
    int tid = threadIdx.x;
    for (int e = tid; e < 512 * 20; e += 256) { int o = e / 512, h = e % 512; wt[h * 20 + o] = w[e]; }
    __syncthreads();
    int gid = blockIdx.x * 256 + tid;
    if (gid >= 64 * T) return;
    int n = gid / T, t = gid % T;
    const uint64_t* r = sw + ((size_t)n * T + t) * 8;
    uint64_t wbuf[8];
#pragma unroll
    for (int wd = 0; wd < 8; ++wd) wbuf[wd] = r[wd];
    double acc[20];
#pragma unroll
    for (int o = 0; o < 20; ++o) acc[o] = 0.0;
#pragma unroll
    for (int wd = 0; wd < 8; ++wd) {
        uint64_t mw = wbuf[wd];
        while (mw) {
            int b = __builtin_ctzll(mw);
            const float* wp = wt + (wd * 64 + b) * 20;
#pragma unroll
            for (int o = 0; o < 20; ++o) acc[o] += (double)wp[o];
            mw &= mw - 1;
        }
    }
#pragma unroll
    for (int o = 0; o < 20; ++o) a[(size_t)t * 1280 + n * 20 + o] = acc[o];
}

// ---------------------------------------------------------------------------
// K4a/KB4a: p[t][row] = sum_k srm[k]*a[t-k][row]  ([t][1280] layout, coalesced)
__global__ __launch_bounds__(256) void k_psp_rows_T(const double* __restrict__ a,
                                                    double* __restrict__ p,
                                                    int total) {
    __shared__ double srm[100];
    int tid = threadIdx.x;
    if (tid < 100) srm[tid] = srm_val(tid);
    __syncthreads();
    int gid = blockIdx.x * 256 + tid;
    if (gid >= total) return;
    int t = gid / 1280, row = gid - t * 1280;
    int kmax = t < 99 ? t : 99;
    double acc = 0.0;
    for (int k = 0; k <= kmax; ++k) acc += srm[k] * a[(size_t)(t - k) * 1280 + row];
    p[gid] = acc;
}

// ---------------------------------------------------------------------------
// K4b/KB4b: sequential spike scan per row; constant-bound register batches.
template<int T, int B>
__global__ __launch_bounds__(256) void k_scan_out_T(const double* __restrict__ p,
                                                    float* __restrict__ out, int off) {
    static_assert(T % B == 0, "batch must divide T");
    __shared__ double refk[32];
    int tid = threadIdx.x;
    if (tid < 32) refk[tid] = ref_val(tid + 1);
    __syncthreads();
    int row = blockIdx.x * 256 + tid;
    if (row >= 1280) return;
    float* orow = out + (size_t)row * 656 + off;
    unsigned mask = 0;
    for (int t0 = 0; t0 < T; t0 += B) {
        double vb[B];
#pragma unroll
        for (int i = 0; i < B; ++i) vb[i] = p[(size_t)(t0 + i) * 1280 + row];
        float ob[B];
#pragma unroll
        for (int i = 0; i < B; ++i) {
            double v = vb[i];
            unsigned m = mask;
            while (m) { int d = __builtin_ctz(m); v += refk[d]; m &= m - 1; }
            int s = (v >= THETA) ? 1 : 0;
            mask = (mask << 1) | (unsigned)s;
            ob[i] = (float)s;
        }
#pragma unroll
        for (int i = 0; i < B; ++i) orow[t0 + i] = ob[i];
    }
}

// ---------------------------------------------------------------------------
// KB1: q[n][j][t] = sum_k srm[k] * x[n][perm[j-k]][t]   (psp over taxel axis)
__global__ __launch_bounds__(256) void k_psp_loc(const float* __restrict__ x,
                                                 const int* __restrict__ perm,
                                                 double* __restrict__ q) {
    __shared__ double srm[100];
    __shared__ int pl[156];
    int tid = threadIdx.x;
    if (tid < 100) srm[tid] = srm_val(tid);
    if (tid < 156) pl[tid] = perm[tid];
    __syncthreads();
    int b = blockIdx.x;
    int row = b >> 1;                  // n*156 + j
    int n = row / 156, j = row % 156;
    int t = ((b & 1) << 8) + tid;
    if (t >= 500) return;
    int kmax = j < 99 ? j : 99;
    double acc = 0.0;
    const float* xn = x + (size_t)n * 156 * 500;
    for (int k = 0; k <= kmax; ++k) {
        int c = pl[j - k];
        acc += srm[k] * (double)xn[(size_t)c * 500 + t];
    }
    q[(size_t)row * 500 + t] = acc;
}

// ---------------------------------------------------------------------------
// KB2: u1b[j][n*512+h] = sum_t w_loc1[h][t] * q[n][j][t]   (fp64 tiled GEMM)
__global__ __launch_bounds__(256) void k_gemm_loc(const double* __restrict__ q,
                                                  const float* __restrict__ wl1,
                                                  double* __restrict__ u1b) {
    __shared__ double At[16][65];   // w [k][h]
    __shared__ double Bt[16][65];   // q [k][j]
    int tid = threadIdx.x;
    int n = blockIdx.x, hb = blockIdx.y, jb = blockIdx.z;
    int th = tid & 15, tj = tid >> 4;
    double acc[4][4];
#pragma unroll
    for (int i = 0; i < 4; ++i)
#pragma unroll
        for (int jj = 0; jj < 4; ++jj) acc[i][jj] = 0.0;
    const double* qn = q + (size_t)n * 156 * 500;
    for (int k0 = 0; k0 < 500; k0 += 16) {
        int KK = (500 - k0 < 16) ? (500 - k0) : 16;
        __syncthreads();
        for (int e = tid; e < 1024; e += 256) {
            int hh = e >> 4, kk = e & 15;
            double v = 0.0;
            if (kk < KK) v = (double)wl1[(size_t)(hb * 64 + hh) * 500 + k0 + kk];
            At[kk][hh] = v;
        }
        for (int e = tid; e < 1024; e += 256) {
            int jj2 = e >> 4, kk = e & 15;
            int j = jb * 64 + jj2;
            double v = 0.0;
            if (j < 156 && kk < KK) v = qn[(size_t)j * 500 + k0 + kk];
            Bt[kk][jj2] = v;
        }
        __syncthreads();
        for (int k = 0; k < KK; ++k) {
            double a0 = At[k][th], a1 = At[k][th + 16], a2v = At[k][th + 32], a3 = At[k][th + 48];
            double b0 = Bt[k][tj], b1 = Bt[k][tj + 16], b2 = Bt[k][tj + 32], b3 = Bt[k][tj + 48];
            acc[0][0] += a0 * b0; acc[0][1] += a0 * b1; acc[0][2] += a0 * b2; acc[0][3] += a0 * b3;
            acc[1][0] += a1 * b0; acc[1][1] += a1 * b1; acc[1][2] += a1 * b2; acc[1][3] += a1 * b3;
            acc[2][0] += a2v * b0; acc[2][1] += a2v * b1; acc[2][2] += a2v * b2; acc[2][3] += a2v * b3;
            acc[3][0] += a3 * b0; acc[3][1] += a3 * b1; acc[3][2] += a3 * b2; acc[3][3] += a3 * b3;
        }
    }
#pragma unroll
    for (int jj = 0; jj < 4; ++jj) {
        int j = jb * 64 + tj + 16 * jj;
        if (j >= 156) continue;
#pragma unroll
        for (int i = 0; i < 4; ++i) {
            int h = hb * 64 + th + 16 * i;
            u1b[(size_t)j * 32768 + n * 512 + h] = acc[i][jj];
        }
    }
}

// ---------------------------------------------------------------------------
// KB2-scan: spike scan over j per (n,h); bit-packed output via ballot.
// s1bw[(n*156+j)*8 + word], word = (h>>6)&7, bit = h&63.
__global__ __launch_bounds__(256) void k_scan_loc1(const double* __restrict__ u1b,
                                                   uint64_t* __restrict__ s1bw) {
    __shared__ double refk[32];
    int tid = threadIdx.x;
    if (tid < 32) refk[tid] = ref_val(tid + 1);
    __syncthreads();
    int gid = blockIdx.x * 256 + tid;     // n*512 + h
    int n = gid >> 9;
    int word = (gid >> 6) & 7;
    int lane = tid & 63;
    unsigned mask = 0;
    for (int j0 = 0; j0 < 156; j0 += 12) {
        double vb[12];
#pragma unroll
        for (int i = 0; i < 12; ++i) vb[i] = u1b[(size_t)(j0 + i) * 32768 + gid];
#pragma unroll
        for (int i = 0; i < 12; ++i) {
            double v = vb[i];
            unsigned m = mask;
            while (m) { int d = __builtin_ctz(m); v += refk[d]; m &= m - 1; }
            int s = (v >= THETA) ? 1 : 0;
            mask = (mask << 1) | (unsigned)s;
            uint64_t bal = __ballot(s != 0);
            if (lane == 0) s1bw[((size_t)n * 156 + (j0 + i)) * 8 + word] = bal;
        }
    }
}

// ---------------------------------------------------------------------------
extern "C" void kernel_launch(void* const* d_in, const int* in_sizes, int n_in,
                              void* d_out, int out_size, void* d_ws, size_t ws_size,
                              hipStream_t stream) {
    const float* x      = (const float*)d_in[0];
    const float* w_fc1  = (const float*)d_in[1];
    const float* w_fc2  = (const float*)d_in[2];
    const float* w_loc1 = (const float*)d_in[3];
    const float* w_loc2 = (const float*)d_in[4];
    const int*   perm   = (const int*)d_in[5];
    float* out = (float*)d_out;
    char* ws = (char*)d_ws;

    // workspace layout (bytes); path B overlays path A's dead buffers
    double*   px   = (double*)(ws + 0);              // 39,936,000 B (q for path B overlays)
    uint64_t* s1w  = (uint64_t*)(ws + 39936000);     //  2,560,000 B  [n][t][8]
    double*   a2   = (double*)(ws + 42496000);       //  5,120,000 B  [t][1280]
    double*   p2   = (double*)(ws + 47616000);       //  5,120,000 B  [t][1280]
    double*   q    = px;
    double*   u1b  = (double*)(ws + 39936000);       // 40,894,464 B (overlays s1w/a2/p2)
    uint64_t* s1bw = (uint64_t*)(ws + 80830464);     //    638,976 B  [n][j][8]
    double*   a2b  = (double*)(ws + 81469440);       //  1,597,440 B  [j][1280]
    double*   p2b  = (double*)(ws + 83066880);       //  1,597,440 B  [j][1280]
    (void)ws_size; (void)in_sizes; (void)n_in; (void)out_size;

    // ---- temporal path ----
    k_psp_time<<<19968, 256, 0, stream>>>(x, px);
    dim3 g2(64, 8);
    k_fused_A<<<g2, 256, 0, stream>>>(px, w_fc1, s1w);
    k_dense2<<<125, 256, 0, stream>>>(s1w, w_fc2, a2, 500);
    k_psp_rows_T<<<2500, 256, 0, stream>>>(a2, p2, 500 * 1280);
    k_scan_out_T<500, 20><<<5, 256, 0, stream>>>(p2, out, 0);

    // ---- location path ----
    k_psp_loc<<<19968, 256, 0, stream>>>(x, perm, q);
    dim3 gb(64, 8, 3);
    k_gemm_loc<<<gb, 256, 0, stream>>>(q, w_loc1, u1b);
    k_scan_loc1<<<128, 256, 0, stream>>>(u1b, s1bw);
    k_dense2<<<39, 256, 0, stream>>>(s1bw, w_loc2, a2b, 156);
    k_psp_rows_T<<<780, 256, 0, stream>>>(a2b, p2b, 156 * 1280);
    k_scan_out_T<156, 12><<<5, 256, 0, stream>>>(p2b, out, 500);
}

// Round 4
// 1894.753 us; speedup vs baseline: 1.2641x; 1.1072x over previous
//
#include <hip/hip_runtime.h>
#include <stdint.h>

#define THETA 10.0

__device__ __forceinline__ double ref_val(int d) {   // refractory kernel at offset d (1..32)
    double t = (double)d;
    return -20.0 * t * exp(1.0 - t);
}

// ---------------------------------------------------------------------------
// S0a: xb[n*500+t][4 words] = bitmask over c (ascending bit = ascending c).
__global__ __launch_bounds__(256) void k_maskA(const float* __restrict__ x,
                                               uint64_t* __restrict__ xb) {
    int gid = blockIdx.x * 256 + threadIdx.x;   // n*500 + t
    if (gid >= 32000) return;
    int n = gid / 500, t = gid - n * 500;
    const float* xn = x + (size_t)n * 78000 + t;
    uint64_t w0 = 0, w1 = 0, w2 = 0;
#pragma unroll
    for (int c = 0; c < 156; ++c) {
        uint64_t bit = (xn[(size_t)c * 500] != 0.0f) ? 1ull : 0ull;
        if (c < 64) w0 |= bit << c;
        else if (c < 128) w1 |= bit << (c - 64);
        else w2 |= bit << (c - 128);
    }
    xb[(size_t)gid * 4 + 0] = w0;
    xb[(size_t)gid * 4 + 1] = w1;
    xb[(size_t)gid * 4 + 2] = w2;
    xb[(size_t)gid * 4 + 3] = 0;
}

// S0b: xbT[n*156+c][8 words] = bitmask over t.
__global__ __launch_bounds__(256) void k_maskB(const float* __restrict__ x,
                                               uint64_t* __restrict__ xbT) {
    int gid = blockIdx.x * 256 + threadIdx.x;   // n*156 + c
    if (gid >= 9984) return;
    const float* row = x + (size_t)gid * 500;
#pragma unroll
    for (int wd = 0; wd < 8; ++wd) {
        uint64_t ww = 0;
        int base = wd * 64;
        int lim = (500 - base < 64) ? (500 - base) : 64;
        for (int b = 0; b < lim; ++b)
            if (row[base + b] != 0.0f) ww |= 1ull << b;
        xbT[(size_t)gid * 8 + wd] = ww;
    }
}

// T0: dst[k*512+h] = src[h*C+k]  (weight transpose to [k][h], f32)
__global__ __launch_bounds__(256) void k_transpose(const float* __restrict__ src,
                                                   float* __restrict__ dst,
                                                   int C, int total) {
    int gid = blockIdx.x * 256 + threadIdx.x;
    if (gid >= total) return;
    int k = gid >> 9, h = gid & 511;
    dst[gid] = src[(size_t)h * C + k];
}

// ---------------------------------------------------------------------------
// A1: sparse dense for t-window w: d1w[tl][n*512+h] = sum_{active c} w1t[c][h]
__global__ __launch_bounds__(256) void k_sdenseA(const uint64_t* __restrict__ xb,
                                                 const float* __restrict__ w1t,
                                                 double* __restrict__ d1w, int w) {
    int tl = blockIdx.x;                        // 0..124
    int n  = blockIdx.y;
    int h  = blockIdx.z * 256 + threadIdx.x;
    int t  = w * 125 + tl;
    const uint64_t* mb = xb + ((size_t)n * 500 + t) * 4;
    double d = 0.0;
#pragma unroll
    for (int wd = 0; wd < 3; ++wd) {
        uint64_t mw = mb[wd];
        while (mw) {
            int b = __builtin_ctzll(mw);
            d += (double)w1t[(size_t)(wd * 64 + b) * 512 + h];
            mw &= mw - 1;
        }
    }
    d1w[(size_t)tl * 32768 + n * 512 + h] = d;
}

// ---------------------------------------------------------------------------
// A2: recurrence-psp + spike scan over one 125-t window; state checkpointed.
// y[t] = 2r y[t-1] - r^2 y[t-2] + g1 d[t-1] + c100 d[t-100] + c101 d[t-101]
__global__ __launch_bounds__(256) void k_rscanA(const double* __restrict__ cur,
                                                const double* __restrict__ prev,
                                                uint64_t* __restrict__ s1w,
                                                double* __restrict__ stY1,
                                                double* __restrict__ stY2,
                                                double* __restrict__ stDp,
                                                uint32_t* __restrict__ stM,
                                                int w) {
    __shared__ double refk[32];
    int tid = threadIdx.x;
    if (tid < 32) refk[tid] = ref_val(tid + 1);
    __syncthreads();
    int gid = blockIdx.x * 256 + tid;           // n*512 + h
    int n = gid >> 9;
    int word = (gid >> 6) & 7;
    int lane = tid & 63;
    double r = exp(-0.1), r2 = r * r, tr = 2.0 * r;
    double g1 = 0.1 * exp(0.9);
    double c100 = -10.0 * exp(-9.0);
    double c101 = 9.9 * exp(-9.1);
    double y1, y2, dp; uint32_t mask;
    if (w == 0) { y1 = 0.0; y2 = 0.0; dp = 0.0; mask = 0u; }
    else { y1 = stY1[gid]; y2 = stY2[gid]; dp = stDp[gid]; mask = stM[gid]; }
    int t0g = w * 125;
    for (int b0 = 0; b0 < 125; b0 += 5) {
        double dc[5], ta[5], tb[5];
#pragma unroll
        for (int i = 0; i < 5; ++i) dc[i] = cur[(size_t)(b0 + i) * 32768 + gid];
#pragma unroll
        for (int i = 0; i < 5; ++i) {
            int tg = t0g + b0 + i;
            int ka = b0 + i - 100;
            int kb = b0 + i - 101;
            ta[i] = (tg >= 100) ? ((ka >= 0) ? cur[(size_t)ka * 32768 + gid]
                                             : prev[(size_t)(125 + ka) * 32768 + gid]) : 0.0;
            tb[i] = (tg >= 101) ? ((kb >= 0) ? cur[(size_t)kb * 32768 + gid]
                                             : prev[(size_t)(125 + kb) * 32768 + gid]) : 0.0;
        }
#pragma unroll
        for (int i = 0; i < 5; ++i) {
            double din = (i == 0) ? dp : dc[i - 1];
            double y = tr * y1 - r2 * y2 + g1 * din + c100 * ta[i] + c101 * tb[i];
            y2 = y1; y1 = y;
            double v = y;
            uint32_t m = mask;
            while (m) { int d = __builtin_ctz(m); v += refk[d]; m &= m - 1; }
            int s = (v >= THETA) ? 1 : 0;
            mask = (mask << 1) | (uint32_t)s;
            uint64_t bal = __ballot(s != 0);
            if (lane == 0) s1w[((size_t)n * 500 + (t0g + b0 + i)) * 8 + word] = bal;
        }
        dp = dc[4];
    }
    stY1[gid] = y1; stY2[gid] = y2; stDp[gid] = dp; stM[gid] = mask;
}

// ---------------------------------------------------------------------------
// K3/KB3: a[t][n*20+o] = sum_h w[o][h] * spike(n,t,h)   (bit-packed spikes)
__global__ __launch_bounds__(256) void k_dense2(const uint64_t* __restrict__ sw,
                                                const float* __restrict__ w,
                                                double* __restrict__ a, int T) {
    __shared__ float wt[512 * 20];
    int tid = threadIdx.x;
    for (int e = tid; e < 512 * 20; e += 256) { int o = e / 512, h = e % 512; wt[h * 20 + o] = w[e]; }
    __syncthreads();
    int gid = blockIdx.x * 256 + tid;
    if (gid >= 64 * T) return;
    int n = gid / T, t = gid % T;
    const uint64_t* r = sw + ((size_t)n * T + t) * 8;
    uint64_t wbuf[8];
#pragma unroll
    for (int wd = 0; wd < 8; ++wd) wbuf[wd] = r[wd];
    double acc[20];
#pragma unroll
    for (int o = 0; o < 20; ++o) acc[o] = 0.0;
#pragma unroll
    for (int wd = 0; wd < 8; ++wd) {
        uint64_t mw = wbuf[wd];
        while (mw) {
            int b = __builtin_ctzll(mw);
            const float* wp = wt + (wd * 64 + b) * 20;
#pragma unroll
            for (int o = 0; o < 20; ++o) acc[o] += (double)wp[o];
            mw &= mw - 1;
        }
    }
#pragma unroll
    for (int o = 0; o < 20; ++o) a[(size_t)t * 1280 + n * 20 + o] = acc[o];
}

// ---------------------------------------------------------------------------
// Layer-2 tail: recurrence-psp + scan per output row; a is [t][1280].
template<int T, int B>
__global__ __launch_bounds__(256) void k_rscan_out(const double* __restrict__ a,
                                                   float* __restrict__ out, int off) {
    static_assert(T % B == 0, "batch must divide T");
    __shared__ double refk[32];
    int tid = threadIdx.x;
    if (tid < 32) refk[tid] = ref_val(tid + 1);
    __syncthreads();
    int row = blockIdx.x * 256 + tid;
    if (row >= 1280) return;
    float* orow = out + (size_t)row * 656 + off;
    double r = exp(-0.1), r2 = r * r, tr = 2.0 * r;
    double g1 = 0.1 * exp(0.9);
    double c100 = -10.0 * exp(-9.0);
    double c101 = 9.9 * exp(-9.1);
    double y1 = 0.0, y2 = 0.0, dp = 0.0; uint32_t mask = 0u;
    for (int t0 = 0; t0 < T; t0 += B) {
        double dc[B], ta[B], tb[B]; float ob[B];
#pragma unroll
        for (int i = 0; i < B; ++i) dc[i] = a[(size_t)(t0 + i) * 1280 + row];
#pragma unroll
        for (int i = 0; i < B; ++i) {
            int t = t0 + i;
            ta[i] = (t >= 100) ? a[(size_t)(t - 100) * 1280 + row] : 0.0;
            tb[i] = (t >= 101) ? a[(size_t)(t - 101) * 1280 + row] : 0.0;
        }
#pragma unroll
        for (int i = 0; i < B; ++i) {
            double din = (i == 0) ? dp : dc[i - 1];
            double y = tr * y1 - r2 * y2 + g1 * din + c100 * ta[i] + c101 * tb[i];
            y2 = y1; y1 = y;
            double v = y;
            uint32_t m = mask;
            while (m) { int d = __builtin_ctz(m); v += refk[d]; m &= m - 1; }
            int s = (v >= THETA) ? 1 : 0;
            mask = (mask << 1) | (uint32_t)s;
            ob[i] = (float)s;
        }
        dp = dc[B - 1];
#pragma unroll
        for (int i = 0; i < B; ++i) orow[t0 + i] = ob[i];
    }
}

// ---------------------------------------------------------------------------
// B1: e[(n*156+c)*512+h] = sum_{active t} wl1t[t][h]   (sparse over t)
__global__ __launch_bounds__(256) void k_sdenseB(const uint64_t* __restrict__ xbT,
                                                 const float* __restrict__ wl1t,
                                                 double* __restrict__ e) {
    int c = blockIdx.x;                         // 156
    int n = blockIdx.y;                         // 64
    int h = blockIdx.z * 256 + threadIdx.x;
    const uint64_t* mb = xbT + ((size_t)n * 156 + c) * 8;
    double d = 0.0;
#pragma unroll
    for (int wd = 0; wd < 8; ++wd) {
        uint64_t mw = mb[wd];
        while (mw) {
            int b = __builtin_ctzll(mw);
            d += (double)wl1t[(size_t)(wd * 64 + b) * 512 + h];
            mw &= mw - 1;
        }
    }
    e[((size_t)n * 156 + c) * 512 + h] = d;
}

// ---------------------------------------------------------------------------
// B2: recurrence-psp over permuted taxel axis + spike scan; bits via ballot.
__global__ __launch_bounds__(256) void k_rscanB(const double* __restrict__ e,
                                                const int* __restrict__ perm,
                                                uint64_t* __restrict__ s1bw) {
    __shared__ double refk[32];
    __shared__ int pl[156];
    int tid = threadIdx.x;
    if (tid < 32) refk[tid] = ref_val(tid + 1);
    if (tid < 156) pl[tid] = perm[tid];
    __syncthreads();
    int gid = blockIdx.x * 256 + tid;           // n*512 + h
    int n = gid >> 9, h = gid & 511;
    int word = (gid >> 6) & 7;
    int lane = tid & 63;
    const double* en = e + (size_t)n * 156 * 512;
    double r = exp(-0.1), r2 = r * r, tr = 2.0 * r;
    double g1 = 0.1 * exp(0.9);
    double c100 = -10.0 * exp(-9.0);
    double c101 = 9.9 * exp(-9.1);
    double y1 = 0.0, y2 = 0.0, dp = 0.0; uint32_t mask = 0u;
    for (int b0 = 0; b0 < 156; b0 += 4) {
        double dc[4], ta[4], tb[4];
#pragma unroll
        for (int i = 0; i < 4; ++i) dc[i] = en[(size_t)pl[b0 + i] * 512 + h];
#pragma unroll
        for (int i = 0; i < 4; ++i) {
            int j = b0 + i;
            ta[i] = (j >= 100) ? en[(size_t)pl[j - 100] * 512 + h] : 0.0;
            tb[i] = (j >= 101) ? en[(size_t)pl[j - 101] * 512 + h] : 0.0;
        }
#pragma unroll
        for (int i = 0; i < 4; ++i) {
            int j = b0 + i;
            double din = (i == 0) ? dp : dc[i - 1];
            double y = tr * y1 - r2 * y2 + g1 * din + c100 * ta[i] + c101 * tb[i];
            y2 = y1; y1 = y;
            double v = y;
            uint32_t m = mask;
            while (m) { int d = __builtin_ctz(m); v += refk[d]; m &= m - 1; }
            int s = (v >= THETA) ? 1 : 0;
            mask = (mask << 1) | (uint32_t)s;
            uint64_t bal = __ballot(s != 0);
            if (lane == 0) s1bw[((size_t)n * 156 + j) * 8 + word] = bal;
        }
        dp = dc[3];
    }
}

// ---------------------------------------------------------------------------
extern "C" void kernel_launch(void* const* d_in, const int* in_sizes, int n_in,
                              void* d_out, int out_size, void* d_ws, size_t ws_size,
                              hipStream_t stream) {
    const float* x      = (const float*)d_in[0];
    const float* w_fc1  = (const float*)d_in[1];
    const float* w_fc2  = (const float*)d_in[2];
    const float* w_loc1 = (const float*)d_in[3];
    const float* w_loc2 = (const float*)d_in[4];
    const int*   perm   = (const int*)d_in[5];
    float* out = (float*)d_out;
    char* ws = (char*)d_ws;
    (void)ws_size; (void)in_sizes; (void)n_in; (void)out_size;

    // region R [0, 65,536,000): d1 window double-buffer; later overlaid by e/a2/a2b
    double*   d1b0 = (double*)(ws + 0);             // 32,768,000 B (125×32768×8)
    double*   d1b1 = (double*)(ws + 32768000);      // 32,768,000 B
    double*   e    = (double*)(ws + 0);             // 40,894,464 B (after path A)
    double*   a2   = (double*)(ws + 40894464);      //  5,120,000 B  [t][1280]
    double*   a2b  = (double*)(ws + 46014464);      //  1,597,440 B  [j][1280]
    // past region R:
    uint64_t* s1w  = (uint64_t*)(ws + 65536000);    //  2,560,000 B  [n][t][8]
    uint64_t* xb   = (uint64_t*)(ws + 68096000);    //  1,024,000 B  [n*500+t][4]
    uint64_t* xbT  = (uint64_t*)(ws + 69120000);    //    638,976 B  [n*156+c][8]
    float*    w1t  = (float*)(ws + 69758976);       //    319,488 B  [c][512]
    float*    wl1t = (float*)(ws + 70078464);       //  1,024,000 B  [t][512]
    uint64_t* s1bw = (uint64_t*)(ws + 71102464);    //    638,976 B  [n][j][8]
    double*   stY1 = (double*)(ws + 71741440);      //    262,144 B
    double*   stY2 = (double*)(ws + 72003584);      //    262,144 B
    double*   stDp = (double*)(ws + 72265728);      //    262,144 B
    uint32_t* stM  = (uint32_t*)(ws + 72527872);    //    131,072 B

    // ---- prep ----
    k_maskA<<<125, 256, 0, stream>>>(x, xb);
    k_maskB<<<39, 256, 0, stream>>>(x, xbT);
    k_transpose<<<312, 256, 0, stream>>>(w_fc1, w1t, 156, 156 * 512);
    k_transpose<<<1000, 256, 0, stream>>>(w_loc1, wl1t, 500, 500 * 512);

    // ---- path A: 4 windows of 125 t ----
    dim3 ga(125, 64, 2);
    for (int w = 0; w < 4; ++w) {
        double* cur = (w & 1) ? d1b1 : d1b0;
        double* prev = (w & 1) ? d1b0 : d1b1;
        k_sdenseA<<<ga, 256, 0, stream>>>(xb, w1t, cur, w);
        k_rscanA<<<128, 256, 0, stream>>>(cur, prev, s1w, stY1, stY2, stDp, stM, w);
    }
    k_dense2<<<125, 256, 0, stream>>>(s1w, w_fc2, a2, 500);
    k_rscan_out<500, 5><<<5, 256, 0, stream>>>(a2, out, 0);

    // ---- path B ----
    dim3 gb(156, 64, 2);
    k_sdenseB<<<gb, 256, 0, stream>>>(xbT, wl1t, e);
    k_rscanB<<<128, 256, 0, stream>>>(e, perm, s1bw);
    k_dense2<<<39, 256, 0, stream>>>(s1bw, w_loc2, a2b, 156);
    k_rscan_out<156, 4><<<5, 256, 0, stream>>>(a2b, out, 500);
}

// Round 5
// 1332.968 us; speedup vs baseline: 1.7969x; 1.4215x over previous
//
#include <hip/hip_runtime.h>
#include <stdint.h>

#define THETA 10.0

// ---------------------------------------------------------------------------
// PREP (one dispatch, block ranges):
//  [0,125)    maskA : xb[n*500+t][4]  bit c over channel axis
//  [125,164)  maskB : xbT[n*156+c][8] bit t over time axis
//  [164,476)  transpose w_fc1  -> w1t[c*512+h]
//  [476,1476) transpose w_loc1 -> wl1t[t*512+h]
__global__ __launch_bounds__(256) void k_prep(const float* __restrict__ x,
                                              const float* __restrict__ w_fc1,
                                              const float* __restrict__ w_loc1,
                                              uint64_t* __restrict__ xb,
                                              uint64_t* __restrict__ xbT,
                                              float* __restrict__ w1t,
                                              float* __restrict__ wl1t) {
    int b = blockIdx.x, tid = threadIdx.x;
    if (b < 125) {
        int gid = b * 256 + tid;                 // n*500 + t
        if (gid >= 32000) return;
        int n = gid / 500, t = gid - n * 500;
        const float* xn = x + (size_t)n * 78000 + t;
        uint64_t w0 = 0, w1 = 0, w2 = 0;
#pragma unroll
        for (int c = 0; c < 156; ++c) {
            uint64_t bit = (xn[(size_t)c * 500] != 0.0f) ? 1ull : 0ull;
            if (c < 64) w0 |= bit << c;
            else if (c < 128) w1 |= bit << (c - 64);
            else w2 |= bit << (c - 128);
        }
        xb[(size_t)gid * 4 + 0] = w0;
        xb[(size_t)gid * 4 + 1] = w1;
        xb[(size_t)gid * 4 + 2] = w2;
        xb[(size_t)gid * 4 + 3] = 0;
    } else if (b < 164) {
        int gid = (b - 125) * 256 + tid;         // n*156 + c
        if (gid >= 9984) return;
        const float* row = x + (size_t)gid * 500;
#pragma unroll
        for (int wd = 0; wd < 8; ++wd) {
            uint64_t ww = 0;
            int base = wd * 64;
            int lim = (500 - base < 64) ? (500 - base) : 64;
            for (int bb = 0; bb < lim; ++bb)
                if (row[base + bb] != 0.0f) ww |= 1ull << bb;
            xbT[(size_t)gid * 8 + wd] = ww;
        }
    } else if (b < 476) {
        int gid = (b - 164) * 256 + tid;         // k*512 + h, 156*512
        int k = gid >> 9, h = gid & 511;
        w1t[gid] = w_fc1[(size_t)h * 156 + k];
    } else {
        int gid = (b - 476) * 256 + tid;         // t*512 + h, 500*512
        int k = gid >> 9, h = gid & 511;
        wl1t[gid] = w_loc1[(size_t)h * 500 + k];
    }
}

// ---------------------------------------------------------------------------
// FUSE1: layer 1 of both paths, fully fused: sparse dense (bit-gather) +
// exact 2nd-order psp recurrence + exact 2nd-order refractory recurrence +
// spike scan. One wave per block; lane = h&63; d-history in LDS (per-thread
// slots, no barrier needed). z=0: temporal path (500 steps over t);
// z=1: location path (156 steps over perm'd taxels).
__global__ __launch_bounds__(64) void k_fuse1(const uint64_t* __restrict__ xb,
                                              const uint64_t* __restrict__ xbT,
                                              const float* __restrict__ w1t,
                                              const float* __restrict__ wl1t,
                                              const int* __restrict__ perm,
                                              uint64_t* __restrict__ s1w,
                                              uint64_t* __restrict__ s1bw) {
    __shared__ double hist[112][64];
    __shared__ int pl[156];
    int tid = threadIdx.x;
    int word = blockIdx.x;                 // h>>6
    int n = blockIdx.y;
    int h = word * 64 + tid;
    // srm recurrence constants (truncated at k<=99)
    double rs = exp(-0.1), trs = 2.0 * rs, r2s = rs * rs;
    double g1 = 0.1 * exp(0.9);
    double c100 = -10.0 * exp(-9.0);
    double c101 = 9.9 * exp(-9.1);
    // refractory recurrence constants (truncated at k<=32)
    double rr = exp(-1.0), trr = 2.0 * rr, r2r = rr * rr;
    double a1 = -20.0;
    double a33 = 660.0 * exp(-32.0);
    double a34 = -640.0 * exp(-33.0);

    double y1 = 0.0, y2 = 0.0, R1 = 0.0, R2 = 0.0, dpv = 0.0;
    uint64_t mask = 0;

    if (blockIdx.z == 0) {
        // ---- temporal path: 500 steps ----
        const uint64_t* mrow = xb + (size_t)n * 500 * 4;
        for (int t0 = 0; t0 < 500; t0 += 4) {
            double dc[4];
#pragma unroll
            for (int i = 0; i < 4; ++i) {
                const uint64_t* mb = mrow + (size_t)(t0 + i) * 4;
                uint64_t m0 = mb[0], m1 = mb[1], m2 = mb[2];
                double d0 = 0.0, d1 = 0.0, d2 = 0.0;
                while (m0) { int bb = __builtin_ctzll(m0); d0 += (double)w1t[(size_t)bb * 512 + h]; m0 &= m0 - 1; }
                while (m1) { int bb = __builtin_ctzll(m1); d1 += (double)w1t[(size_t)(64 + bb) * 512 + h]; m1 &= m1 - 1; }
                while (m2) { int bb = __builtin_ctzll(m2); d2 += (double)w1t[(size_t)(128 + bb) * 512 + h]; m2 &= m2 - 1; }
                dc[i] = (d0 + d1) + d2;
            }
            double ta[4], tb[4];
#pragma unroll
            for (int i = 0; i < 4; ++i) {
                int t = t0 + i;
                ta[i] = (t >= 100) ? hist[(t - 100) % 112][tid] : 0.0;
                tb[i] = (t >= 101) ? hist[(t - 101) % 112][tid] : 0.0;
            }
#pragma unroll
            for (int i = 0; i < 4; ++i) hist[(t0 + i) % 112][tid] = dc[i];
#pragma unroll
            for (int i = 0; i < 4; ++i) {
                int t = t0 + i;
                double din = (i == 0) ? dpv : dc[i - 1];
                double y = trs * y1 - r2s * y2 + g1 * din + c100 * ta[i] + c101 * tb[i];
                y2 = y1; y1 = y;
                double R = trr * R1 - r2r * R2 + a1 * (double)(mask & 1ull)
                         + a33 * (double)((mask >> 32) & 1ull)
                         + a34 * (double)((mask >> 33) & 1ull);
                R2 = R1; R1 = R;
                double v = y + R;
                int s = (v >= THETA) ? 1 : 0;
                mask = (mask << 1) | (uint64_t)s;
                uint64_t bal = __ballot(s != 0);
                if (tid == 0) s1w[((size_t)n * 500 + t) * 8 + word] = bal;
            }
            dpv = dc[3];
        }
    } else {
        // ---- location path: 156 steps over permuted taxels ----
        for (int e = tid; e < 156; e += 64) pl[e] = perm[e];
        __syncthreads();
        const uint64_t* base = xbT + (size_t)n * 156 * 8;
        for (int j0 = 0; j0 < 156; j0 += 4) {
            double dc[4];
#pragma unroll
            for (int i = 0; i < 4; ++i) {
                const uint64_t* mb = base + (size_t)pl[j0 + i] * 8;
                double d = 0.0;
#pragma unroll
                for (int wd = 0; wd < 8; ++wd) {
                    uint64_t mw = mb[wd];
                    while (mw) {
                        int bb = __builtin_ctzll(mw);
                        d += (double)wl1t[(size_t)(wd * 64 + bb) * 512 + h];
                        mw &= mw - 1;
                    }
                }
                dc[i] = d;
            }
            double ta[4], tb[4];
#pragma unroll
            for (int i = 0; i < 4; ++i) {
                int j = j0 + i;
                ta[i] = (j >= 100) ? hist[(j - 100) % 112][tid] : 0.0;
                tb[i] = (j >= 101) ? hist[(j - 101) % 112][tid] : 0.0;
            }
#pragma unroll
            for (int i = 0; i < 4; ++i) hist[(j0 + i) % 112][tid] = dc[i];
#pragma unroll
            for (int i = 0; i < 4; ++i) {
                int j = j0 + i;
                double din = (i == 0) ? dpv : dc[i - 1];
                double y = trs * y1 - r2s * y2 + g1 * din + c100 * ta[i] + c101 * tb[i];
                y2 = y1; y1 = y;
                double R = trr * R1 - r2r * R2 + a1 * (double)(mask & 1ull)
                         + a33 * (double)((mask >> 32) & 1ull)
                         + a34 * (double)((mask >> 33) & 1ull);
                R2 = R1; R1 = R;
                double v = y + R;
                int s = (v >= THETA) ? 1 : 0;
                mask = (mask << 1) | (uint64_t)s;
                uint64_t bal = __ballot(s != 0);
                if (tid == 0) s1bw[((size_t)n * 156 + j) * 8 + word] = bal;
            }
            dpv = dc[3];
        }
    }
}

// ---------------------------------------------------------------------------
// DENSE2 (merged A+B): a[t][n*20+o] = sum_h w[o][h]*spike(n,t,h), bit-packed.
// blocks [0,125): A (T=500, s1w -> a2); [125,164): B (T=156, s1bw -> a2b).
__global__ __launch_bounds__(256) void k_dense2m(const uint64_t* __restrict__ s1w,
                                                 const uint64_t* __restrict__ s1bw,
                                                 const float* __restrict__ w_fc2,
                                                 const float* __restrict__ w_loc2,
                                                 double* __restrict__ a2,
                                                 double* __restrict__ a2b) {
    __shared__ float wt[512 * 20];
    int b = blockIdx.x, tid = threadIdx.x;
    int isA = (b < 125);
    const float* w = isA ? w_fc2 : w_loc2;
    const uint64_t* sw = isA ? s1w : s1bw;
    double* a = isA ? a2 : a2b;
    int T = isA ? 500 : 156;
    int gid = (isA ? b : (b - 125)) * 256 + tid;
    for (int e = tid; e < 512 * 20; e += 256) { int o = e / 512, hh = e % 512; wt[hh * 20 + o] = w[e]; }
    __syncthreads();
    if (gid >= 64 * T) return;
    int n = gid / T, t = gid - n * T;
    const uint64_t* r = sw + ((size_t)n * T + t) * 8;
    uint64_t wbuf[8];
#pragma unroll
    for (int wd = 0; wd < 8; ++wd) wbuf[wd] = r[wd];
    double acc[20];
#pragma unroll
    for (int o = 0; o < 20; ++o) acc[o] = 0.0;
#pragma unroll
    for (int wd = 0; wd < 8; ++wd) {
        uint64_t mw = wbuf[wd];
        while (mw) {
            int bb = __builtin_ctzll(mw);
            const float* wp = wt + (wd * 64 + bb) * 20;
#pragma unroll
            for (int o = 0; o < 20; ++o) acc[o] += (double)wp[o];
            mw &= mw - 1;
        }
    }
#pragma unroll
    for (int o = 0; o < 20; ++o) a[(size_t)t * 1280 + n * 20 + o] = acc[o];
}

// ---------------------------------------------------------------------------
// OUT (merged A+B): recurrence psp + recurrence refractory + scan per row.
// blocks [0,5): A rows (T=500, a2, col off 0); [5,10): B (T=156, a2b, off 500).
__global__ __launch_bounds__(256) void k_rscan_outm(const double* __restrict__ a2,
                                                    const double* __restrict__ a2b,
                                                    float* __restrict__ out) {
    int b = blockIdx.x, tid = threadIdx.x;
    int isA = (b < 5);
    const double* a = isA ? a2 : a2b;
    int T = isA ? 500 : 156;
    int off = isA ? 0 : 500;
    int row = (isA ? b : (b - 5)) * 256 + tid;
    if (row >= 1280) return;
    float* orow = out + (size_t)row * 656 + off;
    double rs = exp(-0.1), trs = 2.0 * rs, r2s = rs * rs;
    double g1 = 0.1 * exp(0.9);
    double c100 = -10.0 * exp(-9.0);
    double c101 = 9.9 * exp(-9.1);
    double rr = exp(-1.0), trr = 2.0 * rr, r2r = rr * rr;
    double a1 = -20.0;
    double a33 = 660.0 * exp(-32.0);
    double a34 = -640.0 * exp(-33.0);
    double y1 = 0.0, y2 = 0.0, R1 = 0.0, R2 = 0.0, dpv = 0.0;
    uint64_t mask = 0;
    for (int t0 = 0; t0 < T; t0 += 4) {
        double dc[4], ta[4], tb[4]; float ob[4];
#pragma unroll
        for (int i = 0; i < 4; ++i) dc[i] = a[(size_t)(t0 + i) * 1280 + row];
#pragma unroll
        for (int i = 0; i < 4; ++i) {
            int t = t0 + i;
            ta[i] = (t >= 100) ? a[(size_t)(t - 100) * 1280 + row] : 0.0;
            tb[i] = (t >= 101) ? a[(size_t)(t - 101) * 1280 + row] : 0.0;
        }
#pragma unroll
        for (int i = 0; i < 4; ++i) {
            double din = (i == 0) ? dpv : dc[i - 1];
            double y = trs * y1 - r2s * y2 + g1 * din + c100 * ta[i] + c101 * tb[i];
            y2 = y1; y1 = y;
            double R = trr * R1 - r2r * R2 + a1 * (double)(mask & 1ull)
                     + a33 * (double)((mask >> 32) & 1ull)
                     + a34 * (double)((mask >> 33) & 1ull);
            R2 = R1; R1 = R;
            double v = y + R;
            int s = (v >= THETA) ? 1 : 0;
            mask = (mask << 1) | (uint64_t)s;
            ob[i] = (float)s;
        }
        dpv = dc[3];
#pragma unroll
        for (int i = 0; i < 4; ++i) orow[t0 + i] = ob[i];
    }
}

// ---------------------------------------------------------------------------
extern "C" void kernel_launch(void* const* d_in, const int* in_sizes, int n_in,
                              void* d_out, int out_size, void* d_ws, size_t ws_size,
                              hipStream_t stream) {
    const float* x      = (const float*)d_in[0];
    const float* w_fc1  = (const float*)d_in[1];
    const float* w_fc2  = (const float*)d_in[2];
    const float* w_loc1 = (const float*)d_in[3];
    const float* w_loc2 = (const float*)d_in[4];
    const int*   perm   = (const int*)d_in[5];
    float* out = (float*)d_out;
    char* ws = (char*)d_ws;
    (void)ws_size; (void)in_sizes; (void)n_in; (void)out_size;

    uint64_t* xb   = (uint64_t*)(ws + 0);           // 1,024,000 B [n*500+t][4]
    uint64_t* xbT  = (uint64_t*)(ws + 1024000);     //   638,976 B [n*156+c][8]
    float*    w1t  = (float*)(ws + 1662976);        //   319,488 B [c][512]
    float*    wl1t = (float*)(ws + 1982464);        // 1,024,000 B [t][512]
    uint64_t* s1w  = (uint64_t*)(ws + 3006464);     // 2,560,000 B [n][t][8]
    uint64_t* s1bw = (uint64_t*)(ws + 5566464);     //   638,976 B [n][j][8]
    double*   a2   = (double*)(ws + 6205440);       // 5,120,000 B [t][1280]
    double*   a2b  = (double*)(ws + 11325440);      // 1,597,440 B [j][1280]

    k_prep<<<1476, 256, 0, stream>>>(x, w_fc1, w_loc1, xb, xbT, w1t, wl1t);
    dim3 g1(8, 64, 2);
    k_fuse1<<<g1, 64, 0, stream>>>(xb, xbT, w1t, wl1t, perm, s1w, s1bw);
    k_dense2m<<<164, 256, 0, stream>>>(s1w, s1bw, w_fc2, w_loc2, a2, a2b);
    k_rscan_outm<<<10, 256, 0, stream>>>(a2, a2b, out);
}

// Round 6
// 617.536 us; speedup vs baseline: 3.8786x; 2.1585x over previous
//
#include <hip/hip_runtime.h>
#include <stdint.h>

#define THETA 10.0

// ---- recurrence constants (exact truncated-kernel equivalents) ------------
struct RC {
    double trs, r2s, g1, c100, c101;   // srm: trunc at k<=99
    double trr, r2r, a1c, a33, a34;    // refractory: trunc at k<=32
};
__device__ __forceinline__ RC make_rc() {
    RC c;
    double rs = exp(-0.1); c.trs = 2.0 * rs; c.r2s = rs * rs;
    c.g1 = 0.1 * exp(0.9); c.c100 = -10.0 * exp(-9.0); c.c101 = 9.9 * exp(-9.1);
    double rr = exp(-1.0); c.trr = 2.0 * rr; c.r2r = rr * rr;
    c.a1c = -20.0; c.a33 = 660.0 * exp(-32.0); c.a34 = -640.0 * exp(-33.0);
    return c;
}
__device__ __forceinline__ int rstep(const RC& c, double din, double ta, double tb,
                                     double& y1, double& y2, double& R1, double& R2,
                                     uint64_t& mask) {
    double y = c.trs * y1 - c.r2s * y2 + c.g1 * din + c.c100 * ta + c.c101 * tb;
    y2 = y1; y1 = y;
    double R = c.trr * R1 - c.r2r * R2 + c.a1c * (double)(mask & 1ull)
             + c.a33 * (double)((mask >> 32) & 1ull)
             + c.a34 * (double)((mask >> 33) & 1ull);
    R2 = R1; R1 = R;
    int s = (y + R >= THETA) ? 1 : 0;
    mask = (mask << 1) | (uint64_t)s;
    return s;
}

// ---------------------------------------------------------------------------
// PREP: input bitmasks (both orientations) + weight transposes. One dispatch.
__global__ __launch_bounds__(256) void k_prep(const float* __restrict__ x,
                                              const float* __restrict__ w_fc1,
                                              const float* __restrict__ w_loc1,
                                              uint64_t* __restrict__ xb,
                                              uint64_t* __restrict__ xbT,
                                              float* __restrict__ w1t,
                                              float* __restrict__ wl1t) {
    int b = blockIdx.x, tid = threadIdx.x;
    if (b < 125) {
        int gid = b * 256 + tid;                 // n*500 + t
        if (gid >= 32000) return;
        int n = gid / 500, t = gid - n * 500;
        const float* xn = x + (size_t)n * 78000 + t;
        uint64_t w0 = 0, w1 = 0, w2 = 0;
#pragma unroll
        for (int c = 0; c < 156; ++c) {
            uint64_t bit = (xn[(size_t)c * 500] != 0.0f) ? 1ull : 0ull;
            if (c < 64) w0 |= bit << c;
            else if (c < 128) w1 |= bit << (c - 64);
            else w2 |= bit << (c - 128);
        }
        xb[(size_t)gid * 4 + 0] = w0;
        xb[(size_t)gid * 4 + 1] = w1;
        xb[(size_t)gid * 4 + 2] = w2;
        xb[(size_t)gid * 4 + 3] = 0;
    } else if (b < 164) {
        int gid = (b - 125) * 256 + tid;         // n*156 + c
        if (gid >= 9984) return;
        const float* row = x + (size_t)gid * 500;
#pragma unroll
        for (int wd = 0; wd < 8; ++wd) {
            uint64_t ww = 0;
            int base = wd * 64;
            int lim = (500 - base < 64) ? (500 - base) : 64;
            for (int bb = 0; bb < lim; ++bb)
                if (row[base + bb] != 0.0f) ww |= 1ull << bb;
            xbT[(size_t)gid * 8 + wd] = ww;
        }
    } else if (b < 476) {
        int gid = (b - 164) * 256 + tid;         // k*512 + h
        int k = gid >> 9, h = gid & 511;
        w1t[gid] = w_fc1[(size_t)h * 156 + k];
    } else {
        int gid = (b - 476) * 256 + tid;         // t*512 + h
        int k = gid >> 9, h = gid & 511;
        wl1t[gid] = w_loc1[(size_t)h * 500 + k];
    }
}

// ---------------------------------------------------------------------------
// A1: sparse dense, window w: d1w[tl][n*512+h] = sum_{active c} w1t[c][h]
__global__ __launch_bounds__(256) void k_sdenseA(const uint64_t* __restrict__ xb,
                                                 const float* __restrict__ w1t,
                                                 double* __restrict__ d1w, int w) {
    int tl = blockIdx.x;                        // 0..124
    int n  = blockIdx.y;
    int h  = blockIdx.z * 256 + threadIdx.x;
    const uint64_t* mb = xb + ((size_t)n * 500 + w * 125 + tl) * 4;
    uint64_t m0 = mb[0], m1 = mb[1], m2 = mb[2];
    double d0 = 0.0, d1 = 0.0, d2 = 0.0;
    while (m0) { int bb = __builtin_ctzll(m0); d0 += (double)w1t[(size_t)bb * 512 + h]; m0 &= m0 - 1; }
    while (m1) { int bb = __builtin_ctzll(m1); d1 += (double)w1t[(size_t)(64 + bb) * 512 + h]; m1 &= m1 - 1; }
    while (m2) { int bb = __builtin_ctzll(m2); d2 += (double)w1t[(size_t)(128 + bb) * 512 + h]; m2 &= m2 - 1; }
    d1w[(size_t)tl * 32768 + n * 512 + h] = (d0 + d1) + d2;
}

// ---------------------------------------------------------------------------
// A2: windowed recurrence scan (psp + refractory), state checkpointed.
template<int B>
__device__ __forceinline__ void scanA_batch(int b0, int t0g,
                                            const double* __restrict__ cur,
                                            const double* __restrict__ prev,
                                            int gid, const RC& rc,
                                            double& y1, double& y2, double& R1, double& R2,
                                            double& dp, uint64_t& mask,
                                            uint64_t* __restrict__ s1w,
                                            int n, int word, int lane) {
    double dc[B], ta[B], tb[B];
#pragma unroll
    for (int i = 0; i < B; ++i) dc[i] = cur[(size_t)(b0 + i) * 32768 + gid];
#pragma unroll
    for (int i = 0; i < B; ++i) {
        int tl = b0 + i, tg = t0g + tl;
        int ka = tl - 100, kb = tl - 101;
        ta[i] = (tg >= 100) ? ((ka >= 0) ? cur[(size_t)ka * 32768 + gid]
                                         : prev[(size_t)(125 + ka) * 32768 + gid]) : 0.0;
        tb[i] = (tg >= 101) ? ((kb >= 0) ? cur[(size_t)kb * 32768 + gid]
                                         : prev[(size_t)(125 + kb) * 32768 + gid]) : 0.0;
    }
#pragma unroll
    for (int i = 0; i < B; ++i) {
        double din = (i == 0) ? dp : dc[i - 1];
        int s = rstep(rc, din, ta[i], tb[i], y1, y2, R1, R2, mask);
        uint64_t bal = __ballot(s != 0);
        if (lane == 0) s1w[((size_t)n * 500 + (t0g + b0 + i)) * 8 + word] = bal;
    }
    dp = dc[B - 1];
}

__global__ __launch_bounds__(256) void k_rscanA(const double* __restrict__ cur,
                                                const double* __restrict__ prev,
                                                uint64_t* __restrict__ s1w,
                                                double* __restrict__ stY1,
                                                double* __restrict__ stY2,
                                                double* __restrict__ stR1,
                                                double* __restrict__ stR2,
                                                double* __restrict__ stDp,
                                                uint64_t* __restrict__ stM,
                                                int w) {
    int tid = threadIdx.x;
    int gid = blockIdx.x * 256 + tid;           // n*512 + h
    int n = gid >> 9, word = (gid >> 6) & 7, lane = tid & 63;
    RC rc = make_rc();
    double y1, y2, R1, R2, dp; uint64_t mask;
    if (w == 0) { y1 = y2 = R1 = R2 = dp = 0.0; mask = 0; }
    else { y1 = stY1[gid]; y2 = stY2[gid]; R1 = stR1[gid]; R2 = stR2[gid];
           dp = stDp[gid]; mask = stM[gid]; }
    int t0g = w * 125;
    for (int b0 = 0; b0 < 120; b0 += 10)
        scanA_batch<10>(b0, t0g, cur, prev, gid, rc, y1, y2, R1, R2, dp, mask, s1w, n, word, lane);
    scanA_batch<5>(120, t0g, cur, prev, gid, rc, y1, y2, R1, R2, dp, mask, s1w, n, word, lane);
    stY1[gid] = y1; stY2[gid] = y2; stR1[gid] = R1; stR2[gid] = R2;
    stDp[gid] = dp; stM[gid] = mask;
}

// ---------------------------------------------------------------------------
// B1: e[(n*156+c)*512+h] = sum_{active t} wl1t[t][h]
__global__ __launch_bounds__(256) void k_sdenseB(const uint64_t* __restrict__ xbT,
                                                 const float* __restrict__ wl1t,
                                                 double* __restrict__ e) {
    int c = blockIdx.x, n = blockIdx.y;
    int h = blockIdx.z * 256 + threadIdx.x;
    const uint64_t* mb = xbT + ((size_t)n * 156 + c) * 8;
    double d = 0.0;
#pragma unroll
    for (int wd = 0; wd < 8; ++wd) {
        uint64_t mw = mb[wd];
        while (mw) {
            int bb = __builtin_ctzll(mw);
            d += (double)wl1t[(size_t)(wd * 64 + bb) * 512 + h];
            mw &= mw - 1;
        }
    }
    e[((size_t)n * 156 + c) * 512 + h] = d;
}

// ---------------------------------------------------------------------------
// B2: recurrence scan over permuted taxel axis (156 steps = 13 x 12).
__global__ __launch_bounds__(256) void k_rscanB(const double* __restrict__ e,
                                                const int* __restrict__ perm,
                                                uint64_t* __restrict__ s1bw) {
    __shared__ int pl[156];
    int tid = threadIdx.x;
    for (int i = tid; i < 156; i += 256) pl[i] = perm[i];
    __syncthreads();
    int gid = blockIdx.x * 256 + tid;           // n*512 + h
    int n = gid >> 9, h = gid & 511, word = (gid >> 6) & 7, lane = tid & 63;
    const double* en = e + (size_t)n * 156 * 512;
    RC rc = make_rc();
    double y1 = 0.0, y2 = 0.0, R1 = 0.0, R2 = 0.0, dp = 0.0; uint64_t mask = 0;
    for (int j0 = 0; j0 < 156; j0 += 12) {
        double dc[12], ta[12], tb[12];
#pragma unroll
        for (int i = 0; i < 12; ++i) dc[i] = en[(size_t)pl[j0 + i] * 512 + h];
#pragma unroll
        for (int i = 0; i < 12; ++i) {
            int j = j0 + i;
            ta[i] = (j >= 100) ? en[(size_t)pl[j - 100] * 512 + h] : 0.0;
            tb[i] = (j >= 101) ? en[(size_t)pl[j - 101] * 512 + h] : 0.0;
        }
#pragma unroll
        for (int i = 0; i < 12; ++i) {
            double din = (i == 0) ? dp : dc[i - 1];
            int s = rstep(rc, din, ta[i], tb[i], y1, y2, R1, R2, mask);
            uint64_t bal = __ballot(s != 0);
            if (lane == 0) s1bw[((size_t)n * 156 + (j0 + i)) * 8 + word] = bal;
        }
        dp = dc[11];
    }
}

// ---------------------------------------------------------------------------
// DENSE2 (merged A+B): a[t][n*20+o] = sum_h w[o][h]*spike(n,t,h), bit-packed.
__global__ __launch_bounds__(256) void k_dense2m(const uint64_t* __restrict__ s1w,
                                                 const uint64_t* __restrict__ s1bw,
                                                 const float* __restrict__ w_fc2,
                                                 const float* __restrict__ w_loc2,
                                                 double* __restrict__ a2,
                                                 double* __restrict__ a2b) {
    __shared__ float wt[512 * 20];
    int b = blockIdx.x, tid = threadIdx.x;
    int isA = (b < 125);
    const float* w = isA ? w_fc2 : w_loc2;
    const uint64_t* sw = isA ? s1w : s1bw;
    double* a = isA ? a2 : a2b;
    int T = isA ? 500 : 156;
    int gid = (isA ? b : (b - 125)) * 256 + tid;
    for (int e = tid; e < 512 * 20; e += 256) { int o = e / 512, hh = e % 512; wt[hh * 20 + o] = w[e]; }
    __syncthreads();
    if (gid >= 64 * T) return;
    int n = gid / T, t = gid - n * T;
    const uint64_t* r = sw + ((size_t)n * T + t) * 8;
    uint64_t wbuf[8];
#pragma unroll
    for (int wd = 0; wd < 8; ++wd) wbuf[wd] = r[wd];
    double acc[20];
#pragma unroll
    for (int o = 0; o < 20; ++o) acc[o] = 0.0;
#pragma unroll
    for (int wd = 0; wd < 8; ++wd) {
        uint64_t mw = wbuf[wd];
        while (mw) {
            int bb = __builtin_ctzll(mw);
            const float* wp = wt + (wd * 64 + bb) * 20;
#pragma unroll
            for (int o = 0; o < 20; ++o) acc[o] += (double)wp[o];
            mw &= mw - 1;
        }
    }
#pragma unroll
    for (int o = 0; o < 20; ++o) a[(size_t)t * 1280 + n * 20 + o] = acc[o];
}

// ---------------------------------------------------------------------------
// OUT (merged A+B): recurrence scan per output row.
template<int T, int B>
__device__ __forceinline__ void out_scan(const double* __restrict__ a,
                                         float* __restrict__ orow, int row) {
    RC rc = make_rc();
    double y1 = 0.0, y2 = 0.0, R1 = 0.0, R2 = 0.0, dp = 0.0; uint64_t mask = 0;
    for (int t0 = 0; t0 < T; t0 += B) {
        double dc[B], ta[B], tb[B]; float ob[B];
#pragma unroll
        for (int i = 0; i < B; ++i) dc[i] = a[(size_t)(t0 + i) * 1280 + row];
#pragma unroll
        for (int i = 0; i < B; ++i) {
            int t = t0 + i;
            ta[i] = (t >= 100) ? a[(size_t)(t - 100) * 1280 + row] : 0.0;
            tb[i] = (t >= 101) ? a[(size_t)(t - 101) * 1280 + row] : 0.0;
        }
#pragma unroll
        for (int i = 0; i < B; ++i) {
            double din = (i == 0) ? dp : dc[i - 1];
            int s = rstep(rc, din, ta[i], tb[i], y1, y2, R1, R2, mask);
            ob[i] = (float)s;
        }
        dp = dc[B - 1];
#pragma unroll
        for (int i = 0; i < B; ++i) orow[t0 + i] = ob[i];
    }
}

__global__ __launch_bounds__(256) void k_outm(const double* __restrict__ a2,
                                              const double* __restrict__ a2b,
                                              float* __restrict__ out) {
    int b = blockIdx.x, tid = threadIdx.x;
    if (b < 5) {
        int row = b * 256 + tid;
        out_scan<500, 10>(a2, out + (size_t)row * 656, row);
    } else {
        int row = (b - 5) * 256 + tid;
        out_scan<156, 12>(a2b, out + (size_t)row * 656 + 500, row);
    }
}

// ---------------------------------------------------------------------------
extern "C" void kernel_launch(void* const* d_in, const int* in_sizes, int n_in,
                              void* d_out, int out_size, void* d_ws, size_t ws_size,
                              hipStream_t stream) {
    const float* x      = (const float*)d_in[0];
    const float* w_fc1  = (const float*)d_in[1];
    const float* w_fc2  = (const float*)d_in[2];
    const float* w_loc1 = (const float*)d_in[3];
    const float* w_loc2 = (const float*)d_in[4];
    const int*   perm   = (const int*)d_in[5];
    float* out = (float*)d_out;
    char* ws = (char*)d_ws;
    (void)ws_size; (void)in_sizes; (void)n_in; (void)out_size;

    // region R [0, 65,536,000): d1 double-buffer (path A), then e / a2 / a2b
    double*   d1b0 = (double*)(ws + 0);             // 32,768,000 B
    double*   d1b1 = (double*)(ws + 32768000);      // 32,768,000 B
    double*   e    = (double*)(ws + 0);             // 40,894,464 B (after A)
    double*   a2   = (double*)(ws + 40894464);      //  5,120,000 B (after B scan)
    double*   a2b  = (double*)(ws + 46014464);      //  1,597,440 B
    // past region R:
    uint64_t* s1w  = (uint64_t*)(ws + 65536000);    //  2,560,000 B
    uint64_t* s1bw = (uint64_t*)(ws + 68096000);    //    638,976 B
    uint64_t* xb   = (uint64_t*)(ws + 68734976);    //  1,024,000 B
    uint64_t* xbT  = (uint64_t*)(ws + 69758976);    //    638,976 B
    float*    w1t  = (float*)(ws + 70397952);       //    319,488 B
    float*    wl1t = (float*)(ws + 70717440);       //  1,024,000 B
    double*   stY1 = (double*)(ws + 71741440);      //    262,144 B
    double*   stY2 = (double*)(ws + 72003584);      //    262,144 B
    double*   stR1 = (double*)(ws + 72265728);      //    262,144 B
    double*   stR2 = (double*)(ws + 72527872);      //    262,144 B
    double*   stDp = (double*)(ws + 72790016);      //    262,144 B
    uint64_t* stM  = (uint64_t*)(ws + 73052160);    //    262,144 B

    k_prep<<<1476, 256, 0, stream>>>(x, w_fc1, w_loc1, xb, xbT, w1t, wl1t);

    // ---- path A: 4 windows of 125 t ----
    dim3 ga(125, 64, 2);
    for (int w = 0; w < 4; ++w) {
        double* cur  = (w & 1) ? d1b1 : d1b0;
        double* prev = (w & 1) ? d1b0 : d1b1;
        k_sdenseA<<<ga, 256, 0, stream>>>(xb, w1t, cur, w);
        k_rscanA<<<128, 256, 0, stream>>>(cur, prev, s1w, stY1, stY2, stR1, stR2, stDp, stM, w);
    }

    // ---- path B ----
    dim3 gb(156, 64, 2);
    k_sdenseB<<<gb, 256, 0, stream>>>(xbT, wl1t, e);
    k_rscanB<<<128, 256, 0, stream>>>(e, perm, s1bw);

    // ---- layer 2 (merged) ----
    k_dense2m<<<164, 256, 0, stream>>>(s1w, s1bw, w_fc2, w_loc2, a2, a2b);
    k_outm<<<10, 256, 0, stream>>>(a2, a2b, out);
}

// Round 8
// 546.232 us; speedup vs baseline: 4.3849x; 1.1305x over previous
//
#include <hip/hip_runtime.h>
#include <stdint.h>

#define THETA 10.0

// ---- recurrence constants (exact truncated-kernel equivalents) ------------
struct RC {
    double trs, r2s, g1, c100, c101;   // srm: trunc at k<=99
    double trr, r2r, a1c, a33, a34;    // refractory: trunc at k<=32
};
__device__ __forceinline__ RC make_rc() {
    RC c;
    double rs = exp(-0.1); c.trs = 2.0 * rs; c.r2s = rs * rs;
    c.g1 = 0.1 * exp(0.9); c.c100 = -10.0 * exp(-9.0); c.c101 = 9.9 * exp(-9.1);
    double rr = exp(-1.0); c.trr = 2.0 * rr; c.r2r = rr * rr;
    c.a1c = -20.0; c.a33 = 660.0 * exp(-32.0); c.a34 = -640.0 * exp(-33.0);
    return c;
}
__device__ __forceinline__ int rstep(const RC& c, double din, double ta, double tb,
                                     double& y1, double& y2, double& R1, double& R2,
                                     uint64_t& mask) {
    double y = c.trs * y1 - c.r2s * y2 + c.g1 * din + c.c100 * ta + c.c101 * tb;
    y2 = y1; y1 = y;
    double R = c.trr * R1 - c.r2r * R2 + c.a1c * (double)(mask & 1ull)
             + c.a33 * (double)((mask >> 32) & 1ull)
             + c.a34 * (double)((mask >> 33) & 1ull);
    R2 = R1; R1 = R;
    int s = (y + R >= THETA) ? 1 : 0;
    mask = (mask << 1) | (uint64_t)s;
    return s;
}

// ---------------------------------------------------------------------------
// PREP: one dispatch, block ranges:
//  [0,125)          maskA: xb[n*500+t][4] bit c   (coalesced over t)
//  [125,20093)      maskB via ballot: wave per (n,c,word)
//  [20093,20117)    w_fc1^T tiles  -> w1t[k*512+h]
//  [20117,20181)    w_loc1^T tiles -> wl1t[k*512+h]
__device__ __forceinline__ void transpose_tile(const float* __restrict__ src,
                                               float* __restrict__ dst,
                                               int C, int k0, int h0, int tid) {
    __shared__ float tile[64][65];
#pragma unroll
    for (int p = 0; p < 16; ++p) {               // 16*256 = 4096 = full 64x64 tile
        int e = tid + p * 256;
        int hh = e >> 6, kk = e & 63;
        int k = k0 + kk;
        tile[hh][kk] = (k < C) ? src[(size_t)(h0 + hh) * C + k] : 0.0f;
    }
    __syncthreads();
#pragma unroll
    for (int p = 0; p < 16; ++p) {
        int e = tid + p * 256;
        int hh = e & 63, kk = e >> 6;
        int k = k0 + kk;
        if (k < C) dst[(size_t)k * 512 + h0 + hh] = tile[hh][kk];
    }
}

__global__ __launch_bounds__(256) void k_prep(const float* __restrict__ x,
                                              const float* __restrict__ w_fc1,
                                              const float* __restrict__ w_loc1,
                                              uint64_t* __restrict__ xb,
                                              uint64_t* __restrict__ xbT,
                                              float* __restrict__ w1t,
                                              float* __restrict__ wl1t) {
    int b = blockIdx.x, tid = threadIdx.x;
    if (b < 125) {
        int gid = b * 256 + tid;                 // n*500 + t
        if (gid >= 32000) return;
        int n = gid / 500, t = gid - n * 500;
        const float* xn = x + (size_t)n * 78000 + t;
        uint64_t w0 = 0, w1 = 0, w2 = 0;
#pragma unroll
        for (int c = 0; c < 156; ++c) {
            uint64_t bit = (xn[(size_t)c * 500] != 0.0f) ? 1ull : 0ull;
            if (c < 64) w0 |= bit << c;
            else if (c < 128) w1 |= bit << (c - 64);
            else w2 |= bit << (c - 128);
        }
        xb[(size_t)gid * 4 + 0] = w0;
        xb[(size_t)gid * 4 + 1] = w1;
        xb[(size_t)gid * 4 + 2] = w2;
        xb[(size_t)gid * 4 + 3] = 0;
    } else if (b < 20093) {
        int idx = (b - 125) * 4 + (tid >> 6);    // (n,c,wd) wave task
        int lane = tid & 63;
        int wd = idx & 7, c = (idx >> 3) % 156, n = idx / 1248;
        int t = wd * 64 + lane;
        float v = (t < 500) ? x[(size_t)n * 78000 + (size_t)c * 500 + t] : 0.0f;
        uint64_t bal = __ballot(v != 0.0f);
        if (lane == 0) xbT[((size_t)n * 156 + c) * 8 + wd] = bal;
    } else if (b < 20117) {
        int tk = b - 20093;                      // 3 k-tiles x 8 h-tiles
        transpose_tile(w_fc1, w1t, 156, (tk >> 3) * 64, (tk & 7) * 64, tid);
    } else {
        int tk = b - 20117;                      // 8 x 8 tiles
        transpose_tile(w_loc1, wl1t, 500, (tk >> 3) * 64, (tk & 7) * 64, tid);
    }
}

// ---------------------------------------------------------------------------
// A1: sparse dense, window w: d1w[tl][n*512+h] = sum_{active c} w1t[c][h]
__global__ __launch_bounds__(256) void k_sdenseA(const uint64_t* __restrict__ xb,
                                                 const float* __restrict__ w1t,
                                                 double* __restrict__ d1w, int w) {
    int tl = blockIdx.x;                        // 0..124
    int n  = blockIdx.y;
    int h  = blockIdx.z * 256 + threadIdx.x;
    const uint64_t* mb = xb + ((size_t)n * 500 + w * 125 + tl) * 4;
    uint64_t m0 = mb[0], m1 = mb[1], m2 = mb[2];
    double d0 = 0.0, d1 = 0.0, d2 = 0.0;
    while (m0) { int bb = __builtin_ctzll(m0); d0 += (double)w1t[(size_t)bb * 512 + h]; m0 &= m0 - 1; }
    while (m1) { int bb = __builtin_ctzll(m1); d1 += (double)w1t[(size_t)(64 + bb) * 512 + h]; m1 &= m1 - 1; }
    while (m2) { int bb = __builtin_ctzll(m2); d2 += (double)w1t[(size_t)(128 + bb) * 512 + h]; m2 &= m2 - 1; }
    d1w[(size_t)tl * 32768 + n * 512 + h] = (d0 + d1) + d2;
}

// ---------------------------------------------------------------------------
// A2: windowed recurrence scan, LDS-staged chunks (barrier-fenced staging).
template<int CH>
__device__ __forceinline__ void scanA_chunk(int b0, int t0g,
    const double* __restrict__ cur, const double* __restrict__ prev,
    int gid, int tid, double (*sdc)[256], double (*sta)[256],
    const RC& rc, double& y1, double& y2, double& R1, double& R2,
    double& dp, uint64_t& mask, uint64_t* __restrict__ s1w,
    int n, int word, int lane) {
#pragma unroll
    for (int i = 0; i < CH; ++i)
        sdc[i][tid] = cur[(size_t)(b0 + i) * 32768 + gid];
#pragma unroll
    for (int i = 0; i <= CH; ++i) {              // d at global step t0g+b0+i-101
        int l = b0 + i - 101;
        double v = 0.0;
        if (t0g + l >= 0)
            v = (l >= 0) ? cur[(size_t)l * 32768 + gid]
                         : prev[(size_t)(125 + l) * 32768 + gid];
        sta[i][tid] = v;
    }
    __syncthreads();
    double dprev = dp;
#pragma unroll
    for (int i = 0; i < CH; ++i) {
        double dc = sdc[i][tid];
        double ta = sta[i + 1][tid];
        double tb = sta[i][tid];
        int s = rstep(rc, dprev, ta, tb, y1, y2, R1, R2, mask);
        uint64_t bal = __ballot(s != 0);
        if (lane == 0) s1w[((size_t)n * 500 + (t0g + b0 + i)) * 8 + word] = bal;
        dprev = dc;
    }
    dp = dprev;
    __syncthreads();
}

__global__ __launch_bounds__(256) void k_rscanA(const double* __restrict__ cur,
                                                const double* __restrict__ prev,
                                                uint64_t* __restrict__ s1w,
                                                double* __restrict__ stY1,
                                                double* __restrict__ stY2,
                                                double* __restrict__ stR1,
                                                double* __restrict__ stR2,
                                                double* __restrict__ stDp,
                                                uint64_t* __restrict__ stM,
                                                int w) {
    __shared__ double sdc[12][256];
    __shared__ double sta[13][256];
    int tid = threadIdx.x;
    int gid = blockIdx.x * 256 + tid;           // n*512 + h
    int n = gid >> 9, word = (gid >> 6) & 7, lane = tid & 63;
    RC rc = make_rc();
    double y1, y2, R1, R2, dp; uint64_t mask;
    if (w == 0) { y1 = y2 = R1 = R2 = dp = 0.0; mask = 0; }
    else { y1 = stY1[gid]; y2 = stY2[gid]; R1 = stR1[gid]; R2 = stR2[gid];
           dp = stDp[gid]; mask = stM[gid]; }
    int t0g = w * 125;
    for (int b0 = 0; b0 < 120; b0 += 12)
        scanA_chunk<12>(b0, t0g, cur, prev, gid, tid, sdc, sta, rc,
                        y1, y2, R1, R2, dp, mask, s1w, n, word, lane);
    scanA_chunk<5>(120, t0g, cur, prev, gid, tid, sdc, sta, rc,
                   y1, y2, R1, R2, dp, mask, s1w, n, word, lane);
    stY1[gid] = y1; stY2[gid] = y2; stR1[gid] = R1; stR2[gid] = R2;
    stDp[gid] = dp; stM[gid] = mask;
}

// ---------------------------------------------------------------------------
// B1: e[(n*156+c)*512+h] = sum_{active t} wl1t[t][h]
__global__ __launch_bounds__(256) void k_sdenseB(const uint64_t* __restrict__ xbT,
                                                 const float* __restrict__ wl1t,
                                                 double* __restrict__ e) {
    int c = blockIdx.x, n = blockIdx.y;
    int h = blockIdx.z * 256 + threadIdx.x;
    const uint64_t* mb = xbT + ((size_t)n * 156 + c) * 8;
    double d = 0.0;
#pragma unroll
    for (int wd = 0; wd < 8; ++wd) {
        uint64_t mw = mb[wd];
        while (mw) {
            int bb = __builtin_ctzll(mw);
            d += (double)wl1t[(size_t)(wd * 64 + bb) * 512 + h];
            mw &= mw - 1;
        }
    }
    e[((size_t)n * 156 + c) * 512 + h] = d;
}

// ---------------------------------------------------------------------------
// B2: recurrence scan over permuted taxel axis, LDS-staged chunks (13 x 12).
__global__ __launch_bounds__(256) void k_rscanB(const double* __restrict__ e,
                                                const int* __restrict__ perm,
                                                uint64_t* __restrict__ s1bw) {
    __shared__ double sdc[12][256];
    __shared__ double sta[13][256];
    __shared__ int pl[156];
    int tid = threadIdx.x;
    for (int i = tid; i < 156; i += 256) pl[i] = perm[i];
    __syncthreads();
    int gid = blockIdx.x * 256 + tid;           // n*512 + h
    int n = gid >> 9, h = gid & 511, word = (gid >> 6) & 7, lane = tid & 63;
    const double* en = e + (size_t)n * 156 * 512;
    RC rc = make_rc();
    double y1 = 0.0, y2 = 0.0, R1 = 0.0, R2 = 0.0, dp = 0.0; uint64_t mask = 0;
    for (int b0 = 0; b0 < 156; b0 += 12) {
#pragma unroll
        for (int i = 0; i < 12; ++i)
            sdc[i][tid] = en[(size_t)pl[b0 + i] * 512 + h];
#pragma unroll
        for (int i = 0; i <= 12; ++i) {
            int l = b0 + i - 101;
            sta[i][tid] = (l >= 0) ? en[(size_t)pl[l] * 512 + h] : 0.0;
        }
        __syncthreads();
        double dprev = dp;
#pragma unroll
        for (int i = 0; i < 12; ++i) {
            double dc = sdc[i][tid];
            double ta = sta[i + 1][tid];
            double tb = sta[i][tid];
            int s = rstep(rc, dprev, ta, tb, y1, y2, R1, R2, mask);
            uint64_t bal = __ballot(s != 0);
            if (lane == 0) s1bw[((size_t)n * 156 + (b0 + i)) * 8 + word] = bal;
            dprev = dc;
        }
        dp = dprev;
        __syncthreads();
    }
}

// ---------------------------------------------------------------------------
// DENSE2 (merged A+B): row-major outputs a2r[row][512], a2br[row][192],
// row = n*20+o (stores coalesced over t).
__global__ __launch_bounds__(256) void k_dense2m(const uint64_t* __restrict__ s1w,
                                                 const uint64_t* __restrict__ s1bw,
                                                 const float* __restrict__ w_fc2,
                                                 const float* __restrict__ w_loc2,
                                                 double* __restrict__ a2r,
                                                 double* __restrict__ a2br) {
    __shared__ float wt[512 * 20];
    int b = blockIdx.x, tid = threadIdx.x;
    int isA = (b < 125);
    const float* w = isA ? w_fc2 : w_loc2;
    const uint64_t* sw = isA ? s1w : s1bw;
    double* a = isA ? a2r : a2br;
    int stride = isA ? 512 : 192;
    int T = isA ? 500 : 156;
    int gid = (isA ? b : (b - 125)) * 256 + tid;
    for (int e = tid; e < 512 * 20; e += 256) { int o = e / 512, hh = e % 512; wt[hh * 20 + o] = w[e]; }
    __syncthreads();
    if (gid >= 64 * T) return;
    int n = gid / T, t = gid - n * T;
    const uint64_t* r = sw + ((size_t)n * T + t) * 8;
    uint64_t wbuf[8];
#pragma unroll
    for (int wd = 0; wd < 8; ++wd) wbuf[wd] = r[wd];
    double acc[20];
#pragma unroll
    for (int o = 0; o < 20; ++o) acc[o] = 0.0;
#pragma unroll
    for (int wd = 0; wd < 8; ++wd) {
        uint64_t mw = wbuf[wd];
        while (mw) {
            int bb = __builtin_ctzll(mw);
            const float* wp = wt + (wd * 64 + bb) * 20;
#pragma unroll
            for (int o = 0; o < 20; ++o) acc[o] += (double)wp[o];
            mw &= mw - 1;
        }
    }
#pragma unroll
    for (int o = 0; o < 20; ++o) a[(size_t)(n * 20 + o) * stride + t] = acc[o];
}

// ---------------------------------------------------------------------------
// OUT: wave-per-row shuffle scan. All lanes redundantly run the recurrence;
// per 64-t chunk: 3 coalesced loads, then register/shuffle-only steps.
template<int LIM>
__device__ __forceinline__ void out_chunk(const double* __restrict__ r,
                                          float* __restrict__ orow, int t0,
                                          const RC& rc, double& y1, double& y2,
                                          double& R1, double& R2, double& dp,
                                          uint64_t& mask, int lane) {
    double x0 = r[t0 + lane];
    int tA = t0 + lane - 100;
    int tB = t0 + lane - 101;
    double xa = (tA >= 0) ? r[tA] : 0.0;
    double xc = (tB >= 0) ? r[tB] : 0.0;
    uint64_t spikes = 0;
    double dprev = dp;
#pragma unroll
    for (int i = 0; i < LIM; ++i) {
        double di = __shfl(x0, i);
        double ta = __shfl(xa, i);
        double tb = __shfl(xc, i);
        int s = rstep(rc, dprev, ta, tb, y1, y2, R1, R2, mask);
        spikes |= (uint64_t)s << i;
        dprev = di;
    }
    dp = dprev;
    if (lane < LIM) orow[t0 + lane] = (float)((spikes >> lane) & 1);
}

__global__ __launch_bounds__(256) void k_outm(const double* __restrict__ a2r,
                                              const double* __restrict__ a2br,
                                              float* __restrict__ out) {
    int b = blockIdx.x, tid = threadIdx.x;
    int wv = tid >> 6, lane = tid & 63;
    RC rc = make_rc();
    double y1 = 0.0, y2 = 0.0, R1 = 0.0, R2 = 0.0, dp = 0.0; uint64_t mask = 0;
    if (b < 320) {
        int row = b * 4 + wv;
        const double* r = a2r + (size_t)row * 512;
        float* orow = out + (size_t)row * 656;
        for (int t0 = 0; t0 < 448; t0 += 64)
            out_chunk<64>(r, orow, t0, rc, y1, y2, R1, R2, dp, mask, lane);
        out_chunk<52>(r, orow, 448, rc, y1, y2, R1, R2, dp, mask, lane);
    } else {
        int row = (b - 320) * 4 + wv;
        const double* r = a2br + (size_t)row * 192;
        float* orow = out + (size_t)row * 656 + 500;
        out_chunk<64>(r, orow, 0, rc, y1, y2, R1, R2, dp, mask, lane);
        out_chunk<64>(r, orow, 64, rc, y1, y2, R1, R2, dp, mask, lane);
        out_chunk<28>(r, orow, 128, rc, y1, y2, R1, R2, dp, mask, lane);
    }
}

// ---------------------------------------------------------------------------
extern "C" void kernel_launch(void* const* d_in, const int* in_sizes, int n_in,
                              void* d_out, int out_size, void* d_ws, size_t ws_size,
                              hipStream_t stream) {
    const float* x      = (const float*)d_in[0];
    const float* w_fc1  = (const float*)d_in[1];
    const float* w_fc2  = (const float*)d_in[2];
    const float* w_loc1 = (const float*)d_in[3];
    const float* w_loc2 = (const float*)d_in[4];
    const int*   perm   = (const int*)d_in[5];
    float* out = (float*)d_out;
    char* ws = (char*)d_ws;
    (void)ws_size; (void)in_sizes; (void)n_in; (void)out_size;

    // region R [0, 65,536,000): d1 double-buffer (path A), then e / a2r / a2br
    double*   d1b0 = (double*)(ws + 0);             // 32,768,000 B
    double*   d1b1 = (double*)(ws + 32768000);      // 32,768,000 B
    double*   e    = (double*)(ws + 0);             // 40,894,464 B (after A)
    double*   a2r  = (double*)(ws + 40894464);      //  5,242,880 B [1280][512]
    double*   a2br = (double*)(ws + 46137344);      //  1,966,080 B [1280][192]
    // past region R:
    uint64_t* s1w  = (uint64_t*)(ws + 65536000);    //  2,560,000 B
    uint64_t* s1bw = (uint64_t*)(ws + 68096000);    //    638,976 B
    uint64_t* xb   = (uint64_t*)(ws + 68734976);    //  1,024,000 B
    uint64_t* xbT  = (uint64_t*)(ws + 69758976);    //    638,976 B
    float*    w1t  = (float*)(ws + 70397952);       //    319,488 B
    float*    wl1t = (float*)(ws + 70717440);       //  1,024,000 B
    double*   stY1 = (double*)(ws + 71741440);      //    262,144 B
    double*   stY2 = (double*)(ws + 72003584);      //    262,144 B
    double*   stR1 = (double*)(ws + 72265728);      //    262,144 B
    double*   stR2 = (double*)(ws + 72527872);      //    262,144 B
    double*   stDp = (double*)(ws + 72790016);      //    262,144 B
    uint64_t* stM  = (uint64_t*)(ws + 73052160);    //    262,144 B

    k_prep<<<20181, 256, 0, stream>>>(x, w_fc1, w_loc1, xb, xbT, w1t, wl1t);

    // ---- path A: 4 windows of 125 t ----
    dim3 ga(125, 64, 2);
    for (int w = 0; w < 4; ++w) {
        double* cur  = (w & 1) ? d1b1 : d1b0;
        double* prev = (w & 1) ? d1b0 : d1b1;
        k_sdenseA<<<ga, 256, 0, stream>>>(xb, w1t, cur, w);
        k_rscanA<<<128, 256, 0, stream>>>(cur, prev, s1w, stY1, stY2, stR1, stR2, stDp, stM, w);
    }

    // ---- path B ----
    dim3 gb(156, 64, 2);
    k_sdenseB<<<gb, 256, 0, stream>>>(xbT, wl1t, e);
    k_rscanB<<<128, 256, 0, stream>>>(e, perm, s1bw);

    // ---- layer 2 (merged) ----
    k_dense2m<<<164, 256, 0, stream>>>(s1w, s1bw, w_fc2, w_loc2, a2r, a2br);
    k_outm<<<640, 256, 0, stream>>>(a2r, a2br, out);
}